// Round 13
// baseline (499.061 us; speedup 1.0000x reference)
//
#include <hip/hip_runtime.h>

#define NTOK 15
#define DP   128
#define DM   768
#define NH   4
#define HD   192
#define NP   64
#define EPSF 1e-5f
#define KW2  384    // [attn(256) | pe(128)]

typedef __attribute__((ext_vector_type(8))) short bf16x8;   // 8 bf16 = 4 VGPR
typedef __attribute__((ext_vector_type(4))) float f32x4;
typedef __attribute__((ext_vector_type(4))) unsigned short us4;

__device__ __forceinline__ unsigned short f2bf(float x) {
    unsigned u = __float_as_uint(x);
    u = (u + 0x7FFF + ((u >> 16) & 1)) >> 16;   // RNE
    return (unsigned short)u;
}
// swizzled LDS byte addresses (row strides 256B / 512B)
__device__ __forceinline__ int swzP(int row, int b) { return row * 256 + (b ^ ((row & 7) << 4)); }
__device__ __forceinline__ int swzB(int row, int b) { return row * 512 + (b ^ ((row & 7) << 4)); }

// ---------------------------------------------------------------------------
// P1: Kraw[hp][192] f32 and Vf[p][768] f32 from protos. 256 blocks x 192 thr.
// ---------------------------------------------------------------------------
__global__ __launch_bounds__(192) void kv_kernel(
    const float* __restrict__ protos,
    const float* __restrict__ wk, const float* __restrict__ bk,
    const float* __restrict__ wv, const float* __restrict__ bv,
    float* __restrict__ Kraw, float* __restrict__ Vf)
{
    int r  = blockIdx.x >> 2;          // proto 0..63
    int jc = blockIdx.x & 3;           // col-chunk
    int j  = jc * 192 + threadIdx.x;   // col 0..767
    __shared__ float prow[DM];
    for (int i = threadIdx.x; i < DM; i += 192) prow[i] = protos[r * DM + i];
    __syncthreads();
    float aK = bk[j], aV = bv[j];
    for (int d = 0; d < DM; ++d) {
        float p = prow[d];
        aK += p * wk[d * DM + j];
        aV += p * wv[d * DM + j];
    }
    int h = j / HD, jj = j - h * HD;
    Kraw[(h * NP + r) * HD + jj] = aK;
    Vf[r * DM + j] = aV;
}

// ---------------------------------------------------------------------------
// P2: fold K/V into weights + build Wcat.
// ---------------------------------------------------------------------------
__global__ __launch_bounds__(256) void fold_kernel(
    const float* __restrict__ Kraw, const float* __restrict__ Vf,
    const float* __restrict__ wq, const float* __restrict__ bq,
    const float* __restrict__ wo, const float* __restrict__ wp,
    unsigned short* __restrict__ KWb, float* __restrict__ kqb,
    unsigned short* __restrict__ Wcat)
{
    int b = blockIdx.x, tid = threadIdx.x;
    if (b >= 256) {
        int idx = (b - 256) * 256 + tid;
        int j = idx >> 7, d = idx & 127;
        Wcat[(size_t)j * KW2 + 256 + d] = f2bf(wp[d * DM + j]);
        return;
    }
    int hp = b, h = hp >> 6, p = hp & 63;
    __shared__ float Kl[HD], Vl[HD];
    if (tid < HD) {
        Kl[tid] = Kraw[hp * HD + tid];
        Vl[tid] = Vf[p * DM + h * HD + tid];
    }
    __syncthreads();
    const float scale = 0.07216878364870323f;   // 1/sqrt(192)
    if (tid < DP) {
        float a = 0.f;
        for (int l = 0; l < HD; ++l) a += wq[tid * DM + h * HD + l] * Kl[l];
        KWb[hp * DP + tid] = f2bf(scale * a);
    } else if (tid == DP) {
        float a = 0.f;
        for (int l = 0; l < HD; ++l) a += bq[h * HD + l] * Kl[l];
        kqb[hp] = scale * a;
    }
    for (int jj = 0; jj < 3; ++jj) {
        int j = jj * 256 + tid;
        float a = 0.f;
        for (int l = 0; l < HD; ++l) a += wo[(h * HD + l) * DM + j] * Vl[l];
        Wcat[(size_t)j * KW2 + hp] = f2bf(a);
    }
}

// ---------------------------------------------------------------------------
// Phase A (r11-verified): 2 state-rows (32 token-rows) per block, 256 thr.
// pe build -> LN -> scores (MFMA) -> softmax -> [attn|pe] bf16 rows to abufG.
// ---------------------------------------------------------------------------
__global__ __launch_bounds__(256, 4) void phaseA_kernel(
    const float* __restrict__ state,
    const float* __restrict__ w_scalar, const float* __restrict__ b_scalar,
    const float* __restrict__ w_patch,  const float* __restrict__ b_patch,
    const float* __restrict__ feat_emb,
    const float* __restrict__ pn_g, const float* __restrict__ pn_b,
    const unsigned short* __restrict__ KWb, const float* __restrict__ kqb,
    unsigned short* __restrict__ abufG, int Nrows)
{
    int tid = threadIdx.x;
    int w = tid >> 6, lane = tid & 63;
    int kg = lane >> 4, lr = lane & 15;
    int nb = blockIdx.x;
    size_t rowbase = (size_t)nb * 32;

    __shared__ float peF[32 * DP];                 // 16KB
    __shared__ __align__(16) char pebf[32 * 256];  // 8KB swizzled bf16
    __shared__ float srow[72];

    if (tid < 72) {
        int rr = tid / 36;
        int gr = nb * 2 + rr;
        srow[tid] = (gr < Nrows) ? state[(size_t)gr * 36 + (tid - rr * 36)] : 0.f;
    }
    __syncthreads();

    // ---- build pe f32 (32 rows x 128) ------------------------------------
    #pragma unroll
    for (int it = 0; it < 16; ++it) {
        int idx = it * 256 + tid;
        int row = idx >> 7, d = idx & 127;
        int t = row & 15;
        const float* sr = &srow[(row >> 4) * 36];
        float val;
        if (t == 15) {
            val = 0.f;
        } else if (t == 0) {
            val = sr[5]  * w_scalar[0 * DP + d] + b_scalar[0 * DP + d] + feat_emb[0 * DP + d];
        } else if (t == 1) {
            val = sr[11] * w_scalar[1 * DP + d] + b_scalar[1 * DP + d] + feat_emb[1 * DP + d];
        } else if (t == 14) {
            val = sr[35] * w_scalar[2 * DP + d] + b_scalar[2 * DP + d] + feat_emb[5 * DP + d];
        } else {
            int f = (t - 2) / 4;
            int k = (t - 2) % 4;
            const float* pr = &sr[(2 + f) * 6];
            float acc = b_patch[f * DP + d] + feat_emb[(2 + f) * DP + d];
            for (int p = 0; p < 3; ++p) acc += pr[k + p] * w_patch[(f * 3 + p) * DP + d];
            val = acc;
        }
        peF[row * DP + d] = val;
    }
    __syncthreads();

    // ---- LayerNorm -> pebf bf16 swizzled (8 lanes per token-row) ---------
    {
        int g = tid >> 3, ln = tid & 7;     // g = 0..31
        int t = g & 15;
        int gr = nb * 2 + (g >> 4);
        if (t == 15 || gr >= Nrows) {
            for (int d = ln; d < DP; d += 8)
                *(unsigned short*)(pebf + swzP(g, d * 2)) = 0;
        } else {
            float s = 0.f, s2 = 0.f;
            for (int d = ln; d < DP; d += 8) { float x = peF[g * DP + d]; s += x; s2 += x * x; }
            for (int off = 4; off; off >>= 1) {
                s  += __shfl_xor(s,  off, 64);
                s2 += __shfl_xor(s2, off, 64);
            }
            float m   = s / DP;
            float var = s2 / DP - m * m;
            float rin = 1.0f / sqrtf(var + EPSF);
            for (int d = ln; d < DP; d += 8) {
                float x = (peF[g * DP + d] - m) * rin * pn_g[d] + pn_b[d];
                *(unsigned short*)(pebf + swzP(g, d * 2)) = f2bf(x);
            }
        }
    }
    __syncthreads();

    // ---- scores = KW @ pe^T + kqb; softmax; attn -> abufG ----------------
    {
        const int h = w;                       // wave == head
        const unsigned short* kwh = KWb + (size_t)h * NP * DP;
        bf16x8 ka[4][4];
        float4 kqv[4];
        #pragma unroll
        for (int Mt = 0; Mt < 4; ++Mt) {
            #pragma unroll
            for (int kk = 0; kk < 4; ++kk)
                ka[Mt][kk] = *(const bf16x8*)(kwh + (Mt * 16 + lr) * DP + kk * 32 + kg * 8);
            kqv[Mt] = *(const float4*)(kqb + h * 64 + Mt * 16 + kg * 4);
        }
        #pragma unroll
        for (int Ntl = 0; Ntl < 2; ++Ntl) {
            bf16x8 qb[4];
            #pragma unroll
            for (int kk = 0; kk < 4; ++kk)
                qb[kk] = *(const bf16x8*)(pebf + swzP(Ntl * 16 + lr, (kk * 32 + kg * 8) * 2));
            f32x4 sacc[4];
            #pragma unroll
            for (int Mt = 0; Mt < 4; ++Mt) sacc[Mt] = (f32x4){0.f, 0.f, 0.f, 0.f};
            #pragma unroll
            for (int kk = 0; kk < 4; ++kk)
                #pragma unroll
                for (int Mt = 0; Mt < 4; ++Mt)
                    sacc[Mt] = __builtin_amdgcn_mfma_f32_16x16x32_bf16(ka[Mt][kk], qb[kk], sacc[Mt], 0, 0, 0);
            #pragma unroll
            for (int Mt = 0; Mt < 4; ++Mt) {
                sacc[Mt][0] += kqv[Mt].x; sacc[Mt][1] += kqv[Mt].y;
                sacc[Mt][2] += kqv[Mt].z; sacc[Mt][3] += kqv[Mt].w;
            }
            float mx = -3.4e38f;
            #pragma unroll
            for (int Mt = 0; Mt < 4; ++Mt)
                #pragma unroll
                for (int r = 0; r < 4; ++r) mx = fmaxf(mx, sacc[Mt][r]);
            mx = fmaxf(mx, __shfl_xor(mx, 16, 64));
            mx = fmaxf(mx, __shfl_xor(mx, 32, 64));
            float sum = 0.f;
            f32x4 ee[4];
            #pragma unroll
            for (int Mt = 0; Mt < 4; ++Mt)
                #pragma unroll
                for (int r = 0; r < 4; ++r) { float e = __expf(sacc[Mt][r] - mx); ee[Mt][r] = e; sum += e; }
            sum += __shfl_xor(sum, 16, 64);
            sum += __shfl_xor(sum, 32, 64);
            float inv = 1.0f / sum;
            unsigned short* dst = abufG + (rowbase + Ntl * 16 + lr) * KW2 + h * 64 + kg * 4;
            #pragma unroll
            for (int Mt = 0; Mt < 4; ++Mt) {
                us4 v = { f2bf(ee[Mt][0] * inv), f2bf(ee[Mt][1] * inv),
                          f2bf(ee[Mt][2] * inv), f2bf(ee[Mt][3] * inv) };
                *(us4*)(dst + Mt * 16) = v;
            }
        }
    }

    // ---- pe bf16 -> abufG cols 256..383 (coalesced 16B) ------------------
    #pragma unroll
    for (int c = 0; c < 2; ++c) {
        int idx = c * 256 + tid;            // 0..511
        int row = idx >> 4, chunk = idx & 15;
        bf16x8 v = *(const bf16x8*)(pebf + swzP(row, chunk * 16));
        *(bf16x8*)(abufG + (rowbase + row) * KW2 + 256 + chunk * 8) = v;
    }
}

// ---------------------------------------------------------------------------
// Phase B: out = LN(A[64x384] @ Wcat^T + bias).
// r11 K-loop (direct global A reads, no barriers) + 8-row stage (24.7KB LDS)
// -> 4 blocks/CU for latency hiding.
// ---------------------------------------------------------------------------
__global__ __launch_bounds__(512, 4) void phaseB_kernel(
    const unsigned short* __restrict__ abufG,
    const unsigned short* __restrict__ Wcat,
    const float* __restrict__ bp, const float* __restrict__ bo,
    const float* __restrict__ on_g, const float* __restrict__ on_b,
    float* __restrict__ out, int Nrows)
{
    int tid = threadIdx.x;
    int w = tid >> 6, lane = tid & 63;
    int kg = lane >> 4, lr = lane & 15;
    int nb = blockIdx.x;
    const int n0 = w * 96;

    __shared__ __align__(16) float stage[8 * 772];      // 24.7KB
    __shared__ float redS[8][64], redS2[8][64];

    const unsigned short* aptr = abufG + (size_t)nb * 64 * KW2;

    float gcol[6], bcol[6];
    f32x4 acc[6][4];
    #pragma unroll
    for (int nt = 0; nt < 6; ++nt) {
        int col = n0 + nt * 16 + lr;
        gcol[nt] = on_g[col]; bcol[nt] = on_b[col];
        float bias = bo[col] + bp[col];
        #pragma unroll
        for (int Mt = 0; Mt < 4; ++Mt) acc[nt][Mt] = (f32x4){bias, bias, bias, bias};
    }

    // ---- K-loop: 12 steps, fully unrolled, no barriers -------------------
    #pragma unroll
    for (int ks = 0; ks < 12; ++ks) {
        bf16x8 aw[4];
        #pragma unroll
        for (int Mt = 0; Mt < 4; ++Mt)
            aw[Mt] = *(const bf16x8*)(aptr + (Mt * 16 + lr) * KW2 + ks * 32 + kg * 8);
        #pragma unroll
        for (int nt = 0; nt < 6; ++nt) {
            bf16x8 b = *(const bf16x8*)(Wcat + (size_t)(n0 + nt * 16 + lr) * KW2 + ks * 32 + kg * 8);
            #pragma unroll
            for (int Mt = 0; Mt < 4; ++Mt)
                acc[nt][Mt] = __builtin_amdgcn_mfma_f32_16x16x32_bf16(aw[Mt], b, acc[nt][Mt], 0, 0, 0);
        }
    }

    // ---- LN stats --------------------------------------------------------
    #pragma unroll
    for (int Mt = 0; Mt < 4; ++Mt)
        #pragma unroll
        for (int r = 0; r < 4; ++r) {
            float s = 0.f, q = 0.f;
            #pragma unroll
            for (int nt = 0; nt < 6; ++nt) { float v = acc[nt][Mt][r]; s += v; q += v * v; }
            #pragma unroll
            for (int off = 8; off; off >>= 1) {
                s += __shfl_xor(s, off, 64);
                q += __shfl_xor(q, off, 64);
            }
            if (lr == 0) {
                int tok = Mt * 16 + kg * 4 + r;
                redS [w][tok] = s;
                redS2[w][tok] = q;
            }
        }
    __syncthreads();
    float mA[4][4], riA[4][4];
    #pragma unroll
    for (int Mt = 0; Mt < 4; ++Mt)
        #pragma unroll
        for (int r = 0; r < 4; ++r) {
            int tok = Mt * 16 + kg * 4 + r;
            float ts = 0.f, tq = 0.f;
            #pragma unroll
            for (int ww = 0; ww < 8; ++ww) { ts += redS[ww][tok]; tq += redS2[ww][tok]; }
            float mm  = ts / DM;
            float var = tq / DM - mm * mm;
            mA[Mt][r]  = mm;
            riA[Mt][r] = 1.0f / sqrtf(var + EPSF);
        }

    // ---- staged coalesced write: 8 token-rows at a time ------------------
    #pragma unroll
    for (int Mt = 0; Mt < 4; ++Mt) {
        int gr = nb * 4 + Mt;
        #pragma unroll
        for (int hh = 0; hh < 2; ++hh) {
            __syncthreads();
            if ((kg >> 1) == hh) {
                #pragma unroll
                for (int nt = 0; nt < 6; ++nt)
                    #pragma unroll
                    for (int r = 0; r < 4; ++r)
                        stage[((kg & 1) * 4 + r) * 772 + n0 + nt * 16 + lr] =
                            (acc[nt][Mt][r] - mA[Mt][r]) * riA[Mt][r] * gcol[nt] + bcol[nt];
            }
            __syncthreads();
            if (gr < Nrows) {
                #pragma unroll
                for (int v = 0; v < 3; ++v) {
                    int f = v * 512 + tid;          // 0..1535
                    int row8 = f / 192, c4 = f - row8 * 192;
                    int tok = hh * 8 + row8;
                    if (tok < NTOK)
                        *(float4*)(out + ((size_t)gr * NTOK + tok) * DM + c4 * 4) =
                            *(const float4*)(&stage[row8 * 772 + c4 * 4]);
                }
            }
        }
    }
}

// ---------------------------------------------------------------------------
// Fallback: fused kernel (used only if ws_size too small for abuf).
// ---------------------------------------------------------------------------
__global__ __launch_bounds__(512, 4) void row_fused_kernel(
    const float* __restrict__ state,
    const float* __restrict__ w_scalar, const float* __restrict__ b_scalar,
    const float* __restrict__ w_patch,  const float* __restrict__ b_patch,
    const float* __restrict__ feat_emb,
    const float* __restrict__ pn_g, const float* __restrict__ pn_b,
    const unsigned short* __restrict__ KWb, const float* __restrict__ kqb,
    const unsigned short* __restrict__ Wcat,
    const float* __restrict__ bp, const float* __restrict__ bo,
    const float* __restrict__ on_g, const float* __restrict__ on_b,
    float* __restrict__ out, int Nrows)
{
    int tid = threadIdx.x;
    int w = tid >> 6, lane = tid & 63;
    int kg = lane >> 4, lr = lane & 15;
    int nb = blockIdx.x;

    __shared__ __align__(16) char bufA[64 * 512];
    __shared__ __align__(16) char pebf[64 * 256];
    __shared__ float srow[4 * 36];
    __shared__ float redS[8][64], redS2[8][64];

    float* peF = (float*)bufA;

    if (tid < 4 * 36) {
        int rr = tid / 36;
        int gr = nb * 4 + rr;
        srow[tid] = (gr < Nrows) ? state[(size_t)gr * 36 + (tid - rr * 36)] : 0.f;
    }
    __syncthreads();

    for (int idx = tid; idx < 4 * NTOK * DP; idx += 512) {
        int rr  = idx / (NTOK * DP);
        int rem = idx - rr * (NTOK * DP);
        int t = rem >> 7, d = rem & 127;
        const float* sr = &srow[rr * 36];
        float val;
        if (t == 0) {
            val = sr[5]  * w_scalar[0 * DP + d] + b_scalar[0 * DP + d] + feat_emb[0 * DP + d];
        } else if (t == 1) {
            val = sr[11] * w_scalar[1 * DP + d] + b_scalar[1 * DP + d] + feat_emb[1 * DP + d];
        } else if (t == 14) {
            val = sr[35] * w_scalar[2 * DP + d] + b_scalar[2 * DP + d] + feat_emb[5 * DP + d];
        } else {
            int f = (t - 2) / 4;
            int k = (t - 2) % 4;
            const float* pr = &sr[(2 + f) * 6];
            float acc = b_patch[f * DP + d] + feat_emb[(2 + f) * DP + d];
            for (int p = 0; p < 3; ++p) acc += pr[k + p] * w_patch[(f * 3 + p) * DP + d];
            val = acc;
        }
        peF[(rr * 16 + t) * DP + d] = val;
    }
    __syncthreads();

    const int h = w >> 1;
    bf16x8 ka[4][4];
    float4 kqv[4];
    {
        const unsigned short* kwh = KWb + (size_t)h * NP * DP;
        #pragma unroll
        for (int Mt = 0; Mt < 4; ++Mt) {
            #pragma unroll
            for (int kk = 0; kk < 4; ++kk)
                ka[Mt][kk] = *(const bf16x8*)(kwh + (Mt * 16 + lr) * DP + kk * 32 + kg * 8);
            kqv[Mt] = *(const float4*)(kqb + h * 64 + Mt * 16 + kg * 4);
        }
    }

    {
        int g = tid >> 3, ln = tid & 7;
        int t = g & 15;
        int gr = nb * 4 + (g >> 4);
        if (t == 15 || gr >= Nrows) {
            for (int d = ln; d < DP; d += 8)
                *(unsigned short*)(pebf + swzP(g, d * 2)) = 0;
        } else {
            float s = 0.f, s2 = 0.f;
            for (int d = ln; d < DP; d += 8) { float x = peF[g * DP + d]; s += x; s2 += x * x; }
            for (int off = 4; off; off >>= 1) {
                s  += __shfl_xor(s,  off, 64);
                s2 += __shfl_xor(s2, off, 64);
            }
            float m   = s / DP;
            float var = s2 / DP - m * m;
            float rin = 1.0f / sqrtf(var + EPSF);
            for (int d = ln; d < DP; d += 8) {
                float x = (peF[g * DP + d] - m) * rin * pn_g[d] + pn_b[d];
                *(unsigned short*)(pebf + swzP(g, d * 2)) = f2bf(x);
            }
        }
    }
    __syncthreads();

    {
        int Nt0 = (w & 1) * 2;
        #pragma unroll
        for (int Ntl = 0; Ntl < 2; ++Ntl) {
            int Nt = Nt0 + Ntl;
            bf16x8 qb[4];
            #pragma unroll
            for (int kk = 0; kk < 4; ++kk)
                qb[kk] = *(const bf16x8*)(pebf + swzP(Nt * 16 + lr, (kk * 32 + kg * 8) * 2));
            f32x4 sacc[4];
            #pragma unroll
            for (int Mt = 0; Mt < 4; ++Mt) sacc[Mt] = (f32x4){0.f, 0.f, 0.f, 0.f};
            #pragma unroll
            for (int kk = 0; kk < 4; ++kk)
                #pragma unroll
                for (int Mt = 0; Mt < 4; ++Mt)
                    sacc[Mt] = __builtin_amdgcn_mfma_f32_16x16x32_bf16(ka[Mt][kk], qb[kk], sacc[Mt], 0, 0, 0);
            #pragma unroll
            for (int Mt = 0; Mt < 4; ++Mt) {
                sacc[Mt][0] += kqv[Mt].x; sacc[Mt][1] += kqv[Mt].y;
                sacc[Mt][2] += kqv[Mt].z; sacc[Mt][3] += kqv[Mt].w;
            }
            float mx = -3.4e38f;
            #pragma unroll
            for (int Mt = 0; Mt < 4; ++Mt)
                #pragma unroll
                for (int r = 0; r < 4; ++r) mx = fmaxf(mx, sacc[Mt][r]);
            mx = fmaxf(mx, __shfl_xor(mx, 16, 64));
            mx = fmaxf(mx, __shfl_xor(mx, 32, 64));
            float sum = 0.f;
            f32x4 ee[4];
            #pragma unroll
            for (int Mt = 0; Mt < 4; ++Mt)
                #pragma unroll
                for (int r = 0; r < 4; ++r) { float e = __expf(sacc[Mt][r] - mx); ee[Mt][r] = e; sum += e; }
            sum += __shfl_xor(sum, 16, 64);
            sum += __shfl_xor(sum, 32, 64);
            float inv = 1.0f / sum;
            #pragma unroll
            for (int Mt = 0; Mt < 4; ++Mt)
                #pragma unroll
                for (int r = 0; r < 4; ++r) {
                    int c = h * 64 + Mt * 16 + kg * 4 + r;
                    *(unsigned short*)(bufA + swzB(Nt * 16 + lr, c * 2)) = f2bf(ee[Mt][r] * inv);
                }
        }
    }
    __syncthreads();

    const int n0 = w * 96;
    #pragma unroll
    for (int half = 0; half < 2; ++half) {
        f32x4 acc[6][2];
        #pragma unroll
        for (int nt = 0; nt < 6; ++nt) {
            int col = n0 + nt * 16 + lr;
            float bias = bo[col] + bp[col];
            acc[nt][0] = (f32x4){bias, bias, bias, bias};
            acc[nt][1] = (f32x4){bias, bias, bias, bias};
        }
        #pragma unroll
        for (int kkc = 0; kkc < 3; ++kkc) {
            #pragma unroll
            for (int kk = 0; kk < 4; ++kk) {
                bf16x8 aw0, aw1;
                if (kkc < 2) {
                    aw0 = *(const bf16x8*)(bufA + swzB((half * 2 + 0) * 16 + lr, (kkc * 128 + kk * 32 + kg * 8) * 2));
                    aw1 = *(const bf16x8*)(bufA + swzB((half * 2 + 1) * 16 + lr, (kkc * 128 + kk * 32 + kg * 8) * 2));
                } else {
                    aw0 = *(const bf16x8*)(pebf + swzP((half * 2 + 0) * 16 + lr, (kk * 32 + kg * 8) * 2));
                    aw1 = *(const bf16x8*)(pebf + swzP((half * 2 + 1) * 16 + lr, (kk * 32 + kg * 8) * 2));
                }
                int ks = kkc * 4 + kk;
                #pragma unroll
                for (int nt = 0; nt < 6; ++nt) {
                    bf16x8 b = *(const bf16x8*)(Wcat + (size_t)(n0 + nt * 16 + lr) * KW2 + ks * 32 + kg * 8);
                    acc[nt][0] = __builtin_amdgcn_mfma_f32_16x16x32_bf16(aw0, b, acc[nt][0], 0, 0, 0);
                    acc[nt][1] = __builtin_amdgcn_mfma_f32_16x16x32_bf16(aw1, b, acc[nt][1], 0, 0, 0);
                }
            }
        }
        #pragma unroll
        for (int Mtl = 0; Mtl < 2; ++Mtl)
            #pragma unroll
            for (int r = 0; r < 4; ++r) {
                float s = 0.f, q = 0.f;
                #pragma unroll
                for (int nt = 0; nt < 6; ++nt) { float v = acc[nt][Mtl][r]; s += v; q += v * v; }
                #pragma unroll
                for (int off = 8; off; off >>= 1) {
                    s += __shfl_xor(s, off, 64);
                    q += __shfl_xor(q, off, 64);
                }
                if (lr == 0) {
                    int tok = (half * 2 + Mtl) * 16 + kg * 4 + r;
                    redS [w][tok] = s;
                    redS2[w][tok] = q;
                }
            }
        __syncthreads();
        #pragma unroll
        for (int Mtl = 0; Mtl < 2; ++Mtl) {
            float mA[4], riA[4];
            #pragma unroll
            for (int r = 0; r < 4; ++r) {
                int tok = (half * 2 + Mtl) * 16 + kg * 4 + r;
                float ts = 0.f, tq = 0.f;
                #pragma unroll
                for (int ww = 0; ww < 8; ++ww) { ts += redS[ww][tok]; tq += redS2[ww][tok]; }
                float mm  = ts / DM;
                float var = tq / DM - mm * mm;
                mA[r]  = mm;
                riA[r] = 1.0f / sqrtf(var + EPSF);
            }
            #pragma unroll
            for (int nt = 0; nt < 6; ++nt) {
                int col = n0 + nt * 16 + lr;
                float g = on_g[col], bb = on_b[col];
                #pragma unroll
                for (int r = 0; r < 4; ++r) {
                    int tok = (half * 2 + Mtl) * 16 + kg * 4 + r;
                    int t = tok & 15, rr = tok >> 4;
                    int gr = nb * 4 + rr;
                    if (t < NTOK && gr < Nrows)
                        out[((size_t)gr * NTOK + t) * DM + col] =
                            (acc[nt][Mtl][r] - mA[r]) * riA[r] * g + bb;
                }
            }
        }
    }
}

extern "C" void kernel_launch(void* const* d_in, const int* in_sizes, int n_in,
                              void* d_out, int out_size, void* d_ws, size_t ws_size,
                              hipStream_t stream) {
    const float* state    = (const float*)d_in[0];
    const float* w_scalar = (const float*)d_in[1];
    const float* b_scalar = (const float*)d_in[2];
    const float* w_patch  = (const float*)d_in[3];
    const float* b_patch  = (const float*)d_in[4];
    const float* feat_emb = (const float*)d_in[5];
    const float* pn_g     = (const float*)d_in[6];
    const float* pn_b     = (const float*)d_in[7];
    const float* wq       = (const float*)d_in[8];
    const float* bq       = (const float*)d_in[9];
    const float* wk       = (const float*)d_in[10];
    const float* bk       = (const float*)d_in[11];
    const float* wv       = (const float*)d_in[12];
    const float* bv       = (const float*)d_in[13];
    const float* wp       = (const float*)d_in[14];
    const float* bp       = (const float*)d_in[15];
    const float* wo       = (const float*)d_in[16];
    const float* bo       = (const float*)d_in[17];
    const float* on_g     = (const float*)d_in[18];
    const float* on_b     = (const float*)d_in[19];
    const float* protos   = (const float*)d_in[20];
    float* out = (float*)d_out;

    float*          Kraw = (float*)d_ws;                    // 49152 f32
    float*          Vf   = Kraw + 256 * HD;                 // 49152 f32
    float*          kqbp = Vf + NP * DM;                    // 256   f32
    unsigned short* KWb  = (unsigned short*)(kqbp + 256);   // 32768 us
    unsigned short* Wcat = KWb + 256 * DP;                  // 294912 us
    unsigned short* abufG = Wcat + (size_t)DM * KW2;

    int N = in_sizes[0] / 36;
    int nblkA = (N + 1) / 2;
    int nblkB = (N + 3) / 4;
    size_t tokrows = (size_t)nblkB * 64;
    size_t need = 1049600ull + tokrows * KW2 * 2ull;        // base + abuf bytes

    hipLaunchKernelGGL(kv_kernel, dim3(256), dim3(192), 0, stream,
                       protos, wk, bk, wv, bv, Kraw, Vf);
    hipLaunchKernelGGL(fold_kernel, dim3(640), dim3(256), 0, stream,
                       Kraw, Vf, wq, bq, wo, wp, KWb, kqbp, Wcat);

    if (ws_size >= need) {
        hipLaunchKernelGGL(phaseA_kernel, dim3(nblkA), dim3(256), 0, stream,
                           state, w_scalar, b_scalar, w_patch, b_patch, feat_emb,
                           pn_g, pn_b, KWb, kqbp, abufG, N);
        hipLaunchKernelGGL(phaseB_kernel, dim3(nblkB), dim3(512), 0, stream,
                           abufG, Wcat, bp, bo, on_g, on_b, out, N);
    } else {
        hipLaunchKernelGGL(row_fused_kernel, dim3(nblkB), dim3(512), 0, stream,
                           state, w_scalar, b_scalar, w_patch, b_patch, feat_emb,
                           pn_g, pn_b, KWb, kqbp, Wcat, bp, bo, on_g, on_b,
                           out, N);
    }
}

// Round 16
// 344.927 us; speedup vs baseline: 1.4469x; 1.4469x over previous
//
#include <hip/hip_runtime.h>

#define NTOK 15
#define DP   128
#define DM   768
#define NH   4
#define HD   192
#define NP   64
#define EPSF 1e-5f
#define KW2  384    // [attn(256) | pe(128)]

typedef __attribute__((ext_vector_type(8))) short bf16x8;   // 8 bf16 = 4 VGPR
typedef __attribute__((ext_vector_type(4))) float f32x4;
typedef __attribute__((ext_vector_type(4))) unsigned short us4;

__device__ __forceinline__ unsigned short f2bf(float x) {
    unsigned u = __float_as_uint(x);
    u = (u + 0x7FFF + ((u >> 16) & 1)) >> 16;   // RNE
    return (unsigned short)u;
}
// swizzled LDS byte addresses (row strides 256B / 512B)
__device__ __forceinline__ int swzP(int row, int b) { return row * 256 + (b ^ ((row & 7) << 4)); }
__device__ __forceinline__ int swzB(int row, int b) { return row * 512 + (b ^ ((row & 7) << 4)); }

// ---------------------------------------------------------------------------
// P1: Kraw[hp][192] f32 and Vf[p][768] f32 from protos.
// 64 blocks x 192 thr, float4 over j (4 cols/thread).
// ---------------------------------------------------------------------------
__global__ __launch_bounds__(192) void kv_kernel(
    const float* __restrict__ protos,
    const float* __restrict__ wk, const float* __restrict__ bk,
    const float* __restrict__ wv, const float* __restrict__ bv,
    float* __restrict__ Kraw, float* __restrict__ Vf)
{
    int r  = blockIdx.x;               // proto 0..63
    int j0 = threadIdx.x * 4;          // col 0,4,...,764
    __shared__ float prow[DM];
    ((float4*)prow)[threadIdx.x] = ((const float4*)protos)[r * 192 + threadIdx.x];
    __syncthreads();
    float4 aK = *(const float4*)(bk + j0);
    float4 aV = *(const float4*)(bv + j0);
    #pragma unroll 2
    for (int d = 0; d < DM; ++d) {
        float p = prow[d];
        float4 k4 = *(const float4*)(wk + d * DM + j0);
        float4 v4 = *(const float4*)(wv + d * DM + j0);
        aK.x += p * k4.x; aK.y += p * k4.y; aK.z += p * k4.z; aK.w += p * k4.w;
        aV.x += p * v4.x; aV.y += p * v4.y; aV.z += p * v4.z; aV.w += p * v4.w;
    }
    int h = j0 / HD, jj = j0 - h * HD;
    *(float4*)(Kraw + (h * NP + r) * HD + jj) = aK;
    *(float4*)(Vf + r * DM + j0) = aV;
}

// ---------------------------------------------------------------------------
// P2: fold K/V into weights + build Wcat.
// ---------------------------------------------------------------------------
__global__ __launch_bounds__(256) void fold_kernel(
    const float* __restrict__ Kraw, const float* __restrict__ Vf,
    const float* __restrict__ wq, const float* __restrict__ bq,
    const float* __restrict__ wo, const float* __restrict__ wp,
    unsigned short* __restrict__ KWb, float* __restrict__ kqb,
    unsigned short* __restrict__ Wcat)
{
    int b = blockIdx.x, tid = threadIdx.x;
    if (b >= 256) {
        int idx = (b - 256) * 256 + tid;
        int j = idx >> 7, d = idx & 127;
        Wcat[(size_t)j * KW2 + 256 + d] = f2bf(wp[d * DM + j]);
        return;
    }
    int hp = b, h = hp >> 6, p = hp & 63;
    __shared__ float Kl[HD], Vl[HD];
    if (tid < HD) {
        Kl[tid] = Kraw[hp * HD + tid];
        Vl[tid] = Vf[p * DM + h * HD + tid];
    }
    __syncthreads();
    const float scale = 0.07216878364870323f;   // 1/sqrt(192)
    if (tid < DP) {
        float a = 0.f;
        for (int l = 0; l < HD; ++l) a += wq[tid * DM + h * HD + l] * Kl[l];
        KWb[hp * DP + tid] = f2bf(scale * a);
    } else if (tid == DP) {
        float a = 0.f;
        for (int l = 0; l < HD; ++l) a += bq[h * HD + l] * Kl[l];
        kqb[hp] = scale * a;
    }
    for (int jj = 0; jj < 3; ++jj) {
        int j = jj * 256 + tid;
        float a = 0.f;
        for (int l = 0; l < HD; ++l) a += wo[(h * HD + l) * DM + j] * Vl[l];
        Wcat[(size_t)j * KW2 + hp] = f2bf(a);
    }
}

// ---------------------------------------------------------------------------
// Phase A (r11-verified): 2 state-rows (32 token-rows) per block, 256 thr.
// ---------------------------------------------------------------------------
__global__ __launch_bounds__(256, 4) void phaseA_kernel(
    const float* __restrict__ state,
    const float* __restrict__ w_scalar, const float* __restrict__ b_scalar,
    const float* __restrict__ w_patch,  const float* __restrict__ b_patch,
    const float* __restrict__ feat_emb,
    const float* __restrict__ pn_g, const float* __restrict__ pn_b,
    const unsigned short* __restrict__ KWb, const float* __restrict__ kqb,
    unsigned short* __restrict__ abufG, int Nrows)
{
    int tid = threadIdx.x;
    int w = tid >> 6, lane = tid & 63;
    int kg = lane >> 4, lr = lane & 15;
    int nb = blockIdx.x;
    size_t rowbase = (size_t)nb * 32;

    __shared__ float peF[32 * DP];                 // 16KB
    __shared__ __align__(16) char pebf[32 * 256];  // 8KB swizzled bf16
    __shared__ float srow[72];

    if (tid < 72) {
        int rr = tid / 36;
        int gr = nb * 2 + rr;
        srow[tid] = (gr < Nrows) ? state[(size_t)gr * 36 + (tid - rr * 36)] : 0.f;
    }
    __syncthreads();

    // ---- build pe f32 (32 rows x 128) ------------------------------------
    #pragma unroll
    for (int it = 0; it < 16; ++it) {
        int idx = it * 256 + tid;
        int row = idx >> 7, d = idx & 127;
        int t = row & 15;
        const float* sr = &srow[(row >> 4) * 36];
        float val;
        if (t == 15) {
            val = 0.f;
        } else if (t == 0) {
            val = sr[5]  * w_scalar[0 * DP + d] + b_scalar[0 * DP + d] + feat_emb[0 * DP + d];
        } else if (t == 1) {
            val = sr[11] * w_scalar[1 * DP + d] + b_scalar[1 * DP + d] + feat_emb[1 * DP + d];
        } else if (t == 14) {
            val = sr[35] * w_scalar[2 * DP + d] + b_scalar[2 * DP + d] + feat_emb[5 * DP + d];
        } else {
            int f = (t - 2) / 4;
            int k = (t - 2) % 4;
            const float* pr = &sr[(2 + f) * 6];
            float acc = b_patch[f * DP + d] + feat_emb[(2 + f) * DP + d];
            for (int p = 0; p < 3; ++p) acc += pr[k + p] * w_patch[(f * 3 + p) * DP + d];
            val = acc;
        }
        peF[row * DP + d] = val;
    }
    __syncthreads();

    // ---- LayerNorm -> pebf bf16 swizzled (8 lanes per token-row) ---------
    {
        int g = tid >> 3, ln = tid & 7;     // g = 0..31
        int t = g & 15;
        int gr = nb * 2 + (g >> 4);
        if (t == 15 || gr >= Nrows) {
            for (int d = ln; d < DP; d += 8)
                *(unsigned short*)(pebf + swzP(g, d * 2)) = 0;
        } else {
            float s = 0.f, s2 = 0.f;
            for (int d = ln; d < DP; d += 8) { float x = peF[g * DP + d]; s += x; s2 += x * x; }
            for (int off = 4; off; off >>= 1) {
                s  += __shfl_xor(s,  off, 64);
                s2 += __shfl_xor(s2, off, 64);
            }
            float m   = s / DP;
            float var = s2 / DP - m * m;
            float rin = 1.0f / sqrtf(var + EPSF);
            for (int d = ln; d < DP; d += 8) {
                float x = (peF[g * DP + d] - m) * rin * pn_g[d] + pn_b[d];
                *(unsigned short*)(pebf + swzP(g, d * 2)) = f2bf(x);
            }
        }
    }
    __syncthreads();

    // ---- scores = KW @ pe^T + kqb; softmax; attn -> abufG ----------------
    {
        const int h = w;                       // wave == head
        const unsigned short* kwh = KWb + (size_t)h * NP * DP;
        bf16x8 ka[4][4];
        float4 kqv[4];
        #pragma unroll
        for (int Mt = 0; Mt < 4; ++Mt) {
            #pragma unroll
            for (int kk = 0; kk < 4; ++kk)
                ka[Mt][kk] = *(const bf16x8*)(kwh + (Mt * 16 + lr) * DP + kk * 32 + kg * 8);
            kqv[Mt] = *(const float4*)(kqb + h * 64 + Mt * 16 + kg * 4);
        }
        #pragma unroll
        for (int Ntl = 0; Ntl < 2; ++Ntl) {
            bf16x8 qb[4];
            #pragma unroll
            for (int kk = 0; kk < 4; ++kk)
                qb[kk] = *(const bf16x8*)(pebf + swzP(Ntl * 16 + lr, (kk * 32 + kg * 8) * 2));
            f32x4 sacc[4];
            #pragma unroll
            for (int Mt = 0; Mt < 4; ++Mt) sacc[Mt] = (f32x4){0.f, 0.f, 0.f, 0.f};
            #pragma unroll
            for (int kk = 0; kk < 4; ++kk)
                #pragma unroll
                for (int Mt = 0; Mt < 4; ++Mt)
                    sacc[Mt] = __builtin_amdgcn_mfma_f32_16x16x32_bf16(ka[Mt][kk], qb[kk], sacc[Mt], 0, 0, 0);
            #pragma unroll
            for (int Mt = 0; Mt < 4; ++Mt) {
                sacc[Mt][0] += kqv[Mt].x; sacc[Mt][1] += kqv[Mt].y;
                sacc[Mt][2] += kqv[Mt].z; sacc[Mt][3] += kqv[Mt].w;
            }
            float mx = -3.4e38f;
            #pragma unroll
            for (int Mt = 0; Mt < 4; ++Mt)
                #pragma unroll
                for (int r = 0; r < 4; ++r) mx = fmaxf(mx, sacc[Mt][r]);
            mx = fmaxf(mx, __shfl_xor(mx, 16, 64));
            mx = fmaxf(mx, __shfl_xor(mx, 32, 64));
            float sum = 0.f;
            f32x4 ee[4];
            #pragma unroll
            for (int Mt = 0; Mt < 4; ++Mt)
                #pragma unroll
                for (int r = 0; r < 4; ++r) { float e = __expf(sacc[Mt][r] - mx); ee[Mt][r] = e; sum += e; }
            sum += __shfl_xor(sum, 16, 64);
            sum += __shfl_xor(sum, 32, 64);
            float inv = 1.0f / sum;
            unsigned short* dst = abufG + (rowbase + Ntl * 16 + lr) * KW2 + h * 64 + kg * 4;
            #pragma unroll
            for (int Mt = 0; Mt < 4; ++Mt) {
                us4 v = { f2bf(ee[Mt][0] * inv), f2bf(ee[Mt][1] * inv),
                          f2bf(ee[Mt][2] * inv), f2bf(ee[Mt][3] * inv) };
                *(us4*)(dst + Mt * 16) = v;
            }
        }
    }

    // ---- pe bf16 -> abufG cols 256..383 (coalesced 16B) ------------------
    #pragma unroll
    for (int c = 0; c < 2; ++c) {
        int idx = c * 256 + tid;            // 0..511
        int row = idx >> 4, chunk = idx & 15;
        bf16x8 v = *(const bf16x8*)(pebf + swzP(row, chunk * 16));
        *(bf16x8*)(abufG + (rowbase + row) * KW2 + 256 + chunk * 8) = v;
    }
}

// ---------------------------------------------------------------------------
// Phase B (r11-verified): out = LN(A[64x384] @ Wcat^T + bias).
// Direct global A reads, no barriers in K-loop; 16-row staged coalesced write.
// Only change vs r11: s_setprio(1) around the MFMA cluster (T5).
// ---------------------------------------------------------------------------
__global__ __launch_bounds__(512, 2) void phaseB_kernel(
    const unsigned short* __restrict__ abufG,
    const unsigned short* __restrict__ Wcat,
    const float* __restrict__ bp, const float* __restrict__ bo,
    const float* __restrict__ on_g, const float* __restrict__ on_b,
    float* __restrict__ out, int Nrows)
{
    int tid = threadIdx.x;
    int w = tid >> 6, lane = tid & 63;
    int kg = lane >> 4, lr = lane & 15;
    int nb = blockIdx.x;
    const int n0 = w * 96;

    __shared__ __align__(16) float stage[16 * 772];      // 49.4KB
    __shared__ float redS[8][64], redS2[8][64];

    const unsigned short* aptr = abufG + (size_t)nb * 64 * KW2;

    float gcol[6], bcol[6];
    f32x4 acc[6][4];
    #pragma unroll
    for (int nt = 0; nt < 6; ++nt) {
        int col = n0 + nt * 16 + lr;
        gcol[nt] = on_g[col]; bcol[nt] = on_b[col];
        float bias = bo[col] + bp[col];
        #pragma unroll
        for (int Mt = 0; Mt < 4; ++Mt) acc[nt][Mt] = (f32x4){bias, bias, bias, bias};
    }

    // ---- K-loop: 12 steps, fully unrolled, no barriers -------------------
    #pragma unroll
    for (int ks = 0; ks < 12; ++ks) {
        bf16x8 aw[4];
        #pragma unroll
        for (int Mt = 0; Mt < 4; ++Mt)
            aw[Mt] = *(const bf16x8*)(aptr + (Mt * 16 + lr) * KW2 + ks * 32 + kg * 8);
        __builtin_amdgcn_s_setprio(1);
        #pragma unroll
        for (int nt = 0; nt < 6; ++nt) {
            bf16x8 b = *(const bf16x8*)(Wcat + (size_t)(n0 + nt * 16 + lr) * KW2 + ks * 32 + kg * 8);
            #pragma unroll
            for (int Mt = 0; Mt < 4; ++Mt)
                acc[nt][Mt] = __builtin_amdgcn_mfma_f32_16x16x32_bf16(aw[Mt], b, acc[nt][Mt], 0, 0, 0);
        }
        __builtin_amdgcn_s_setprio(0);
    }

    // ---- LN stats --------------------------------------------------------
    #pragma unroll
    for (int Mt = 0; Mt < 4; ++Mt)
        #pragma unroll
        for (int r = 0; r < 4; ++r) {
            float s = 0.f, q = 0.f;
            #pragma unroll
            for (int nt = 0; nt < 6; ++nt) { float v = acc[nt][Mt][r]; s += v; q += v * v; }
            #pragma unroll
            for (int off = 8; off; off >>= 1) {
                s += __shfl_xor(s, off, 64);
                q += __shfl_xor(q, off, 64);
            }
            if (lr == 0) {
                int tok = Mt * 16 + kg * 4 + r;
                redS [w][tok] = s;
                redS2[w][tok] = q;
            }
        }
    __syncthreads();
    float mA[4][4], riA[4][4];
    #pragma unroll
    for (int Mt = 0; Mt < 4; ++Mt)
        #pragma unroll
        for (int r = 0; r < 4; ++r) {
            int tok = Mt * 16 + kg * 4 + r;
            float ts = 0.f, tq = 0.f;
            #pragma unroll
            for (int ww = 0; ww < 8; ++ww) { ts += redS[ww][tok]; tq += redS2[ww][tok]; }
            float mm  = ts / DM;
            float var = tq / DM - mm * mm;
            mA[Mt][r]  = mm;
            riA[Mt][r] = 1.0f / sqrtf(var + EPSF);
        }

    // ---- staged coalesced write: one 16-row tile (= one source row) at a time
    #pragma unroll
    for (int Mt = 0; Mt < 4; ++Mt) {
        __syncthreads();
        #pragma unroll
        for (int nt = 0; nt < 6; ++nt)
            #pragma unroll
            for (int r = 0; r < 4; ++r)
                stage[(kg * 4 + r) * 772 + n0 + nt * 16 + lr] =
                    (acc[nt][Mt][r] - mA[Mt][r]) * riA[Mt][r] * gcol[nt] + bcol[nt];
        __syncthreads();
        int gr = nb * 4 + Mt;
        if (gr < Nrows) {
            #pragma unroll
            for (int v = 0; v < 6; ++v) {
                int f = v * 512 + tid;          // 0..3071
                int row = f / 192, c4 = f - row * 192;
                if (row < NTOK)
                    *(float4*)(out + ((size_t)gr * NTOK + row) * DM + c4 * 4) =
                        *(const float4*)(&stage[row * 772 + c4 * 4]);
            }
        }
    }
}

// ---------------------------------------------------------------------------
// Fallback: fused kernel (used only if ws_size too small for abuf).
// ---------------------------------------------------------------------------
__global__ __launch_bounds__(512, 4) void row_fused_kernel(
    const float* __restrict__ state,
    const float* __restrict__ w_scalar, const float* __restrict__ b_scalar,
    const float* __restrict__ w_patch,  const float* __restrict__ b_patch,
    const float* __restrict__ feat_emb,
    const float* __restrict__ pn_g, const float* __restrict__ pn_b,
    const unsigned short* __restrict__ KWb, const float* __restrict__ kqb,
    const unsigned short* __restrict__ Wcat,
    const float* __restrict__ bp, const float* __restrict__ bo,
    const float* __restrict__ on_g, const float* __restrict__ on_b,
    float* __restrict__ out, int Nrows)
{
    int tid = threadIdx.x;
    int w = tid >> 6, lane = tid & 63;
    int kg = lane >> 4, lr = lane & 15;
    int nb = blockIdx.x;

    __shared__ __align__(16) char bufA[64 * 512];
    __shared__ __align__(16) char pebf[64 * 256];
    __shared__ float srow[4 * 36];
    __shared__ float redS[8][64], redS2[8][64];

    float* peF = (float*)bufA;

    if (tid < 4 * 36) {
        int rr = tid / 36;
        int gr = nb * 4 + rr;
        srow[tid] = (gr < Nrows) ? state[(size_t)gr * 36 + (tid - rr * 36)] : 0.f;
    }
    __syncthreads();

    for (int idx = tid; idx < 4 * NTOK * DP; idx += 512) {
        int rr  = idx / (NTOK * DP);
        int rem = idx - rr * (NTOK * DP);
        int t = rem >> 7, d = rem & 127;
        const float* sr = &srow[rr * 36];
        float val;
        if (t == 0) {
            val = sr[5]  * w_scalar[0 * DP + d] + b_scalar[0 * DP + d] + feat_emb[0 * DP + d];
        } else if (t == 1) {
            val = sr[11] * w_scalar[1 * DP + d] + b_scalar[1 * DP + d] + feat_emb[1 * DP + d];
        } else if (t == 14) {
            val = sr[35] * w_scalar[2 * DP + d] + b_scalar[2 * DP + d] + feat_emb[5 * DP + d];
        } else {
            int f = (t - 2) / 4;
            int k = (t - 2) % 4;
            const float* pr = &sr[(2 + f) * 6];
            float acc = b_patch[f * DP + d] + feat_emb[(2 + f) * DP + d];
            for (int p = 0; p < 3; ++p) acc += pr[k + p] * w_patch[(f * 3 + p) * DP + d];
            val = acc;
        }
        peF[(rr * 16 + t) * DP + d] = val;
    }
    __syncthreads();

    const int h = w >> 1;
    bf16x8 ka[4][4];
    float4 kqv[4];
    {
        const unsigned short* kwh = KWb + (size_t)h * NP * DP;
        #pragma unroll
        for (int Mt = 0; Mt < 4; ++Mt) {
            #pragma unroll
            for (int kk = 0; kk < 4; ++kk)
                ka[Mt][kk] = *(const bf16x8*)(kwh + (Mt * 16 + lr) * DP + kk * 32 + kg * 8);
            kqv[Mt] = *(const float4*)(kqb + h * 64 + Mt * 16 + kg * 4);
        }
    }

    {
        int g = tid >> 3, ln = tid & 7;
        int t = g & 15;
        int gr = nb * 4 + (g >> 4);
        if (t == 15 || gr >= Nrows) {
            for (int d = ln; d < DP; d += 8)
                *(unsigned short*)(pebf + swzP(g, d * 2)) = 0;
        } else {
            float s = 0.f, s2 = 0.f;
            for (int d = ln; d < DP; d += 8) { float x = peF[g * DP + d]; s += x; s2 += x * x; }
            for (int off = 4; off; off >>= 1) {
                s  += __shfl_xor(s,  off, 64);
                s2 += __shfl_xor(s2, off, 64);
            }
            float m   = s / DP;
            float var = s2 / DP - m * m;
            float rin = 1.0f / sqrtf(var + EPSF);
            for (int d = ln; d < DP; d += 8) {
                float x = (peF[g * DP + d] - m) * rin * pn_g[d] + pn_b[d];
                *(unsigned short*)(pebf + swzP(g, d * 2)) = f2bf(x);
            }
        }
    }
    __syncthreads();

    {
        int Nt0 = (w & 1) * 2;
        #pragma unroll
        for (int Ntl = 0; Ntl < 2; ++Ntl) {
            int Nt = Nt0 + Ntl;
            bf16x8 qb[4];
            #pragma unroll
            for (int kk = 0; kk < 4; ++kk)
                qb[kk] = *(const bf16x8*)(pebf + swzP(Nt * 16 + lr, (kk * 32 + kg * 8) * 2));
            f32x4 sacc[4];
            #pragma unroll
            for (int Mt = 0; Mt < 4; ++Mt) sacc[Mt] = (f32x4){0.f, 0.f, 0.f, 0.f};
            #pragma unroll
            for (int kk = 0; kk < 4; ++kk)
                #pragma unroll
                for (int Mt = 0; Mt < 4; ++Mt)
                    sacc[Mt] = __builtin_amdgcn_mfma_f32_16x16x32_bf16(ka[Mt][kk], qb[kk], sacc[Mt], 0, 0, 0);
            #pragma unroll
            for (int Mt = 0; Mt < 4; ++Mt) {
                sacc[Mt][0] += kqv[Mt].x; sacc[Mt][1] += kqv[Mt].y;
                sacc[Mt][2] += kqv[Mt].z; sacc[Mt][3] += kqv[Mt].w;
            }
            float mx = -3.4e38f;
            #pragma unroll
            for (int Mt = 0; Mt < 4; ++Mt)
                #pragma unroll
                for (int r = 0; r < 4; ++r) mx = fmaxf(mx, sacc[Mt][r]);
            mx = fmaxf(mx, __shfl_xor(mx, 16, 64));
            mx = fmaxf(mx, __shfl_xor(mx, 32, 64));
            float sum = 0.f;
            f32x4 ee[4];
            #pragma unroll
            for (int Mt = 0; Mt < 4; ++Mt)
                #pragma unroll
                for (int r = 0; r < 4; ++r) { float e = __expf(sacc[Mt][r] - mx); ee[Mt][r] = e; sum += e; }
            sum += __shfl_xor(sum, 16, 64);
            sum += __shfl_xor(sum, 32, 64);
            float inv = 1.0f / sum;
            #pragma unroll
            for (int Mt = 0; Mt < 4; ++Mt)
                #pragma unroll
                for (int r = 0; r < 4; ++r) {
                    int c = h * 64 + Mt * 16 + kg * 4 + r;
                    *(unsigned short*)(bufA + swzB(Nt * 16 + lr, c * 2)) = f2bf(ee[Mt][r] * inv);
                }
        }
    }
    __syncthreads();

    const int n0 = w * 96;
    #pragma unroll
    for (int half = 0; half < 2; ++half) {
        f32x4 acc[6][2];
        #pragma unroll
        for (int nt = 0; nt < 6; ++nt) {
            int col = n0 + nt * 16 + lr;
            float bias = bo[col] + bp[col];
            acc[nt][0] = (f32x4){bias, bias, bias, bias};
            acc[nt][1] = (f32x4){bias, bias, bias, bias};
        }
        #pragma unroll
        for (int kkc = 0; kkc < 3; ++kkc) {
            #pragma unroll
            for (int kk = 0; kk < 4; ++kk) {
                bf16x8 aw0, aw1;
                if (kkc < 2) {
                    aw0 = *(const bf16x8*)(bufA + swzB((half * 2 + 0) * 16 + lr, (kkc * 128 + kk * 32 + kg * 8) * 2));
                    aw1 = *(const bf16x8*)(bufA + swzB((half * 2 + 1) * 16 + lr, (kkc * 128 + kk * 32 + kg * 8) * 2));
                } else {
                    aw0 = *(const bf16x8*)(pebf + swzP((half * 2 + 0) * 16 + lr, (kk * 32 + kg * 8) * 2));
                    aw1 = *(const bf16x8*)(pebf + swzP((half * 2 + 1) * 16 + lr, (kk * 32 + kg * 8) * 2));
                }
                int ks = kkc * 4 + kk;
                #pragma unroll
                for (int nt = 0; nt < 6; ++nt) {
                    bf16x8 b = *(const bf16x8*)(Wcat + (size_t)(n0 + nt * 16 + lr) * KW2 + ks * 32 + kg * 8);
                    acc[nt][0] = __builtin_amdgcn_mfma_f32_16x16x32_bf16(aw0, b, acc[nt][0], 0, 0, 0);
                    acc[nt][1] = __builtin_amdgcn_mfma_f32_16x16x32_bf16(aw1, b, acc[nt][1], 0, 0, 0);
                }
            }
        }
        #pragma unroll
        for (int Mtl = 0; Mtl < 2; ++Mtl)
            #pragma unroll
            for (int r = 0; r < 4; ++r) {
                float s = 0.f, q = 0.f;
                #pragma unroll
                for (int nt = 0; nt < 6; ++nt) { float v = acc[nt][Mtl][r]; s += v; q += v * v; }
                #pragma unroll
                for (int off = 8; off; off >>= 1) {
                    s += __shfl_xor(s, off, 64);
                    q += __shfl_xor(q, off, 64);
                }
                if (lr == 0) {
                    int tok = (half * 2 + Mtl) * 16 + kg * 4 + r;
                    redS [w][tok] = s;
                    redS2[w][tok] = q;
                }
            }
        __syncthreads();
        #pragma unroll
        for (int Mtl = 0; Mtl < 2; ++Mtl) {
            float mA[4], riA[4];
            #pragma unroll
            for (int r = 0; r < 4; ++r) {
                int tok = (half * 2 + Mtl) * 16 + kg * 4 + r;
                float ts = 0.f, tq = 0.f;
                #pragma unroll
                for (int ww = 0; ww < 8; ++ww) { ts += redS[ww][tok]; tq += redS2[ww][tok]; }
                float mm  = ts / DM;
                float var = tq / DM - mm * mm;
                mA[r]  = mm;
                riA[r] = 1.0f / sqrtf(var + EPSF);
            }
            #pragma unroll
            for (int nt = 0; nt < 6; ++nt) {
                int col = n0 + nt * 16 + lr;
                float g = on_g[col], bb = on_b[col];
                #pragma unroll
                for (int r = 0; r < 4; ++r) {
                    int tok = (half * 2 + Mtl) * 16 + kg * 4 + r;
                    int t = tok & 15, rr = tok >> 4;
                    int gr = nb * 4 + rr;
                    if (t < NTOK && gr < Nrows)
                        out[((size_t)gr * NTOK + t) * DM + col] =
                            (acc[nt][Mtl][r] - mA[r]) * riA[r] * g + bb;
                }
            }
        }
    }
}

extern "C" void kernel_launch(void* const* d_in, const int* in_sizes, int n_in,
                              void* d_out, int out_size, void* d_ws, size_t ws_size,
                              hipStream_t stream) {
    const float* state    = (const float*)d_in[0];
    const float* w_scalar = (const float*)d_in[1];
    const float* b_scalar = (const float*)d_in[2];
    const float* w_patch  = (const float*)d_in[3];
    const float* b_patch  = (const float*)d_in[4];
    const float* feat_emb = (const float*)d_in[5];
    const float* pn_g     = (const float*)d_in[6];
    const float* pn_b     = (const float*)d_in[7];
    const float* wq       = (const float*)d_in[8];
    const float* bq       = (const float*)d_in[9];
    const float* wk       = (const float*)d_in[10];
    const float* bk       = (const float*)d_in[11];
    const float* wv       = (const float*)d_in[12];
    const float* bv       = (const float*)d_in[13];
    const float* wp       = (const float*)d_in[14];
    const float* bp       = (const float*)d_in[15];
    const float* wo       = (const float*)d_in[16];
    const float* bo       = (const float*)d_in[17];
    const float* on_g     = (const float*)d_in[18];
    const float* on_b     = (const float*)d_in[19];
    const float* protos   = (const float*)d_in[20];
    float* out = (float*)d_out;

    float*          Kraw = (float*)d_ws;                    // 49152 f32
    float*          Vf   = Kraw + 256 * HD;                 // 49152 f32
    float*          kqbp = Vf + NP * DM;                    // 256   f32
    unsigned short* KWb  = (unsigned short*)(kqbp + 256);   // 32768 us
    unsigned short* Wcat = KWb + 256 * DP;                  // 294912 us
    unsigned short* abufG = Wcat + (size_t)DM * KW2;

    int N = in_sizes[0] / 36;
    int nblkA = (N + 1) / 2;
    int nblkB = (N + 3) / 4;
    size_t tokrows = (size_t)nblkB * 64;
    size_t need = 1049600ull + tokrows * KW2 * 2ull;        // base + abuf bytes

    hipLaunchKernelGGL(kv_kernel, dim3(NP), dim3(192), 0, stream,
                       protos, wk, bk, wv, bv, Kraw, Vf);
    hipLaunchKernelGGL(fold_kernel, dim3(640), dim3(256), 0, stream,
                       Kraw, Vf, wq, bq, wo, wp, KWb, kqbp, Wcat);

    if (ws_size >= need) {
        hipLaunchKernelGGL(phaseA_kernel, dim3(nblkA), dim3(256), 0, stream,
                           state, w_scalar, b_scalar, w_patch, b_patch, feat_emb,
                           pn_g, pn_b, KWb, kqbp, abufG, N);
        hipLaunchKernelGGL(phaseB_kernel, dim3(nblkB), dim3(512), 0, stream,
                           abufG, Wcat, bp, bo, on_g, on_b, out, N);
    } else {
        hipLaunchKernelGGL(row_fused_kernel, dim3(nblkB), dim3(512), 0, stream,
                           state, w_scalar, b_scalar, w_patch, b_patch, feat_emb,
                           pn_g, pn_b, KWb, kqbp, Wcat, bp, bo, on_g, on_b,
                           out, N);
    }
}

// Round 17
// 298.186 us; speedup vs baseline: 1.6737x; 1.1568x over previous
//
#include <hip/hip_runtime.h>

#define NTOK 15
#define DP   128
#define DM   768
#define NH   4
#define HD   192
#define NP   64
#define EPSF 1e-5f
#define KW2  384    // [attn(256) | pe(128)]

typedef __attribute__((ext_vector_type(8))) short bf16x8;   // 8 bf16 = 4 VGPR
typedef __attribute__((ext_vector_type(4))) float f32x4;
typedef __attribute__((ext_vector_type(4))) unsigned short us4;

__device__ __forceinline__ unsigned short f2bf(float x) {
    unsigned u = __float_as_uint(x);
    u = (u + 0x7FFF + ((u >> 16) & 1)) >> 16;   // RNE
    return (unsigned short)u;
}
// swizzled LDS byte addresses (row strides 256B / 512B)
__device__ __forceinline__ int swzP(int row, int b) { return row * 256 + (b ^ ((row & 7) << 4)); }
__device__ __forceinline__ int swzB(int row, int b) { return row * 512 + (b ^ ((row & 7) << 4)); }

// ---------------------------------------------------------------------------
// P1 (r11-verified): Kraw[hp][192] f32 and Vf[p][768] f32 from protos.
// 256 blocks x 192 thr (proto = b>>2, col-chunk = b&3) for CU coverage.
// ---------------------------------------------------------------------------
__global__ __launch_bounds__(192) void kv_kernel(
    const float* __restrict__ protos,
    const float* __restrict__ wk, const float* __restrict__ bk,
    const float* __restrict__ wv, const float* __restrict__ bv,
    float* __restrict__ Kraw, float* __restrict__ Vf)
{
    int r  = blockIdx.x >> 2;          // proto 0..63
    int jc = blockIdx.x & 3;           // col-chunk
    int j  = jc * 192 + threadIdx.x;   // col 0..767
    __shared__ float prow[DM];
    for (int i = threadIdx.x; i < DM; i += 192) prow[i] = protos[r * DM + i];
    __syncthreads();
    float aK = bk[j], aV = bv[j];
    for (int d = 0; d < DM; ++d) {
        float p = prow[d];
        aK += p * wk[d * DM + j];
        aV += p * wv[d * DM + j];
    }
    int h = j / HD, jj = j - h * HD;
    Kraw[(h * NP + r) * HD + jj] = aK;
    Vf[r * DM + j] = aV;
}

// ---------------------------------------------------------------------------
// P2: fold K/V into weights + build Wcat.
// ---------------------------------------------------------------------------
__global__ __launch_bounds__(256) void fold_kernel(
    const float* __restrict__ Kraw, const float* __restrict__ Vf,
    const float* __restrict__ wq, const float* __restrict__ bq,
    const float* __restrict__ wo, const float* __restrict__ wp,
    unsigned short* __restrict__ KWb, float* __restrict__ kqb,
    unsigned short* __restrict__ Wcat)
{
    int b = blockIdx.x, tid = threadIdx.x;
    if (b >= 256) {
        int idx = (b - 256) * 256 + tid;
        int j = idx >> 7, d = idx & 127;
        Wcat[(size_t)j * KW2 + 256 + d] = f2bf(wp[d * DM + j]);
        return;
    }
    int hp = b, h = hp >> 6, p = hp & 63;
    __shared__ float Kl[HD], Vl[HD];
    if (tid < HD) {
        Kl[tid] = Kraw[hp * HD + tid];
        Vl[tid] = Vf[p * DM + h * HD + tid];
    }
    __syncthreads();
    const float scale = 0.07216878364870323f;   // 1/sqrt(192)
    if (tid < DP) {
        float a = 0.f;
        for (int l = 0; l < HD; ++l) a += wq[tid * DM + h * HD + l] * Kl[l];
        KWb[hp * DP + tid] = f2bf(scale * a);
    } else if (tid == DP) {
        float a = 0.f;
        for (int l = 0; l < HD; ++l) a += bq[h * HD + l] * Kl[l];
        kqb[hp] = scale * a;
    }
    for (int jj = 0; jj < 3; ++jj) {
        int j = jj * 256 + tid;
        float a = 0.f;
        for (int l = 0; l < HD; ++l) a += wo[(h * HD + l) * DM + j] * Vl[l];
        Wcat[(size_t)j * KW2 + hp] = f2bf(a);
    }
}

// ---------------------------------------------------------------------------
// Phase A (r11-verified): 2 state-rows (32 token-rows) per block, 256 thr.
// ---------------------------------------------------------------------------
__global__ __launch_bounds__(256, 4) void phaseA_kernel(
    const float* __restrict__ state,
    const float* __restrict__ w_scalar, const float* __restrict__ b_scalar,
    const float* __restrict__ w_patch,  const float* __restrict__ b_patch,
    const float* __restrict__ feat_emb,
    const float* __restrict__ pn_g, const float* __restrict__ pn_b,
    const unsigned short* __restrict__ KWb, const float* __restrict__ kqb,
    unsigned short* __restrict__ abufG, int Nrows)
{
    int tid = threadIdx.x;
    int w = tid >> 6, lane = tid & 63;
    int kg = lane >> 4, lr = lane & 15;
    int nb = blockIdx.x;
    size_t rowbase = (size_t)nb * 32;

    __shared__ float peF[32 * DP];                 // 16KB
    __shared__ __align__(16) char pebf[32 * 256];  // 8KB swizzled bf16
    __shared__ float srow[72];

    if (tid < 72) {
        int rr = tid / 36;
        int gr = nb * 2 + rr;
        srow[tid] = (gr < Nrows) ? state[(size_t)gr * 36 + (tid - rr * 36)] : 0.f;
    }
    __syncthreads();

    // ---- build pe f32 (32 rows x 128) ------------------------------------
    #pragma unroll
    for (int it = 0; it < 16; ++it) {
        int idx = it * 256 + tid;
        int row = idx >> 7, d = idx & 127;
        int t = row & 15;
        const float* sr = &srow[(row >> 4) * 36];
        float val;
        if (t == 15) {
            val = 0.f;
        } else if (t == 0) {
            val = sr[5]  * w_scalar[0 * DP + d] + b_scalar[0 * DP + d] + feat_emb[0 * DP + d];
        } else if (t == 1) {
            val = sr[11] * w_scalar[1 * DP + d] + b_scalar[1 * DP + d] + feat_emb[1 * DP + d];
        } else if (t == 14) {
            val = sr[35] * w_scalar[2 * DP + d] + b_scalar[2 * DP + d] + feat_emb[5 * DP + d];
        } else {
            int f = (t - 2) / 4;
            int k = (t - 2) % 4;
            const float* pr = &sr[(2 + f) * 6];
            float acc = b_patch[f * DP + d] + feat_emb[(2 + f) * DP + d];
            for (int p = 0; p < 3; ++p) acc += pr[k + p] * w_patch[(f * 3 + p) * DP + d];
            val = acc;
        }
        peF[row * DP + d] = val;
    }
    __syncthreads();

    // ---- LayerNorm -> pebf bf16 swizzled (8 lanes per token-row) ---------
    {
        int g = tid >> 3, ln = tid & 7;     // g = 0..31
        int t = g & 15;
        int gr = nb * 2 + (g >> 4);
        if (t == 15 || gr >= Nrows) {
            for (int d = ln; d < DP; d += 8)
                *(unsigned short*)(pebf + swzP(g, d * 2)) = 0;
        } else {
            float s = 0.f, s2 = 0.f;
            for (int d = ln; d < DP; d += 8) { float x = peF[g * DP + d]; s += x; s2 += x * x; }
            for (int off = 4; off; off >>= 1) {
                s  += __shfl_xor(s,  off, 64);
                s2 += __shfl_xor(s2, off, 64);
            }
            float m   = s / DP;
            float var = s2 / DP - m * m;
            float rin = 1.0f / sqrtf(var + EPSF);
            for (int d = ln; d < DP; d += 8) {
                float x = (peF[g * DP + d] - m) * rin * pn_g[d] + pn_b[d];
                *(unsigned short*)(pebf + swzP(g, d * 2)) = f2bf(x);
            }
        }
    }
    __syncthreads();

    // ---- scores = KW @ pe^T + kqb; softmax; attn -> abufG ----------------
    {
        const int h = w;                       // wave == head
        const unsigned short* kwh = KWb + (size_t)h * NP * DP;
        bf16x8 ka[4][4];
        float4 kqv[4];
        #pragma unroll
        for (int Mt = 0; Mt < 4; ++Mt) {
            #pragma unroll
            for (int kk = 0; kk < 4; ++kk)
                ka[Mt][kk] = *(const bf16x8*)(kwh + (Mt * 16 + lr) * DP + kk * 32 + kg * 8);
            kqv[Mt] = *(const float4*)(kqb + h * 64 + Mt * 16 + kg * 4);
        }
        #pragma unroll
        for (int Ntl = 0; Ntl < 2; ++Ntl) {
            bf16x8 qb[4];
            #pragma unroll
            for (int kk = 0; kk < 4; ++kk)
                qb[kk] = *(const bf16x8*)(pebf + swzP(Ntl * 16 + lr, (kk * 32 + kg * 8) * 2));
            f32x4 sacc[4];
            #pragma unroll
            for (int Mt = 0; Mt < 4; ++Mt) sacc[Mt] = (f32x4){0.f, 0.f, 0.f, 0.f};
            #pragma unroll
            for (int kk = 0; kk < 4; ++kk)
                #pragma unroll
                for (int Mt = 0; Mt < 4; ++Mt)
                    sacc[Mt] = __builtin_amdgcn_mfma_f32_16x16x32_bf16(ka[Mt][kk], qb[kk], sacc[Mt], 0, 0, 0);
            #pragma unroll
            for (int Mt = 0; Mt < 4; ++Mt) {
                sacc[Mt][0] += kqv[Mt].x; sacc[Mt][1] += kqv[Mt].y;
                sacc[Mt][2] += kqv[Mt].z; sacc[Mt][3] += kqv[Mt].w;
            }
            float mx = -3.4e38f;
            #pragma unroll
            for (int Mt = 0; Mt < 4; ++Mt)
                #pragma unroll
                for (int r = 0; r < 4; ++r) mx = fmaxf(mx, sacc[Mt][r]);
            mx = fmaxf(mx, __shfl_xor(mx, 16, 64));
            mx = fmaxf(mx, __shfl_xor(mx, 32, 64));
            float sum = 0.f;
            f32x4 ee[4];
            #pragma unroll
            for (int Mt = 0; Mt < 4; ++Mt)
                #pragma unroll
                for (int r = 0; r < 4; ++r) { float e = __expf(sacc[Mt][r] - mx); ee[Mt][r] = e; sum += e; }
            sum += __shfl_xor(sum, 16, 64);
            sum += __shfl_xor(sum, 32, 64);
            float inv = 1.0f / sum;
            unsigned short* dst = abufG + (rowbase + Ntl * 16 + lr) * KW2 + h * 64 + kg * 4;
            #pragma unroll
            for (int Mt = 0; Mt < 4; ++Mt) {
                us4 v = { f2bf(ee[Mt][0] * inv), f2bf(ee[Mt][1] * inv),
                          f2bf(ee[Mt][2] * inv), f2bf(ee[Mt][3] * inv) };
                *(us4*)(dst + Mt * 16) = v;
            }
        }
    }

    // ---- pe bf16 -> abufG cols 256..383 (coalesced 16B) ------------------
    #pragma unroll
    for (int c = 0; c < 2; ++c) {
        int idx = c * 256 + tid;            // 0..511
        int row = idx >> 4, chunk = idx & 15;
        bf16x8 v = *(const bf16x8*)(pebf + swzP(row, chunk * 16));
        *(bf16x8*)(abufG + (rowbase + row) * KW2 + 256 + chunk * 8) = v;
    }
}

// ---------------------------------------------------------------------------
// Phase B: out = LN(A[64x384] @ Wcat^T + bias).
// Direct global A reads, no barriers in K-loop; 16-row staged coalesced write.
// s_setprio(1) around the MFMA cluster (T5).
// ---------------------------------------------------------------------------
__global__ __launch_bounds__(512, 2) void phaseB_kernel(
    const unsigned short* __restrict__ abufG,
    const unsigned short* __restrict__ Wcat,
    const float* __restrict__ bp, const float* __restrict__ bo,
    const float* __restrict__ on_g, const float* __restrict__ on_b,
    float* __restrict__ out, int Nrows)
{
    int tid = threadIdx.x;
    int w = tid >> 6, lane = tid & 63;
    int kg = lane >> 4, lr = lane & 15;
    int nb = blockIdx.x;
    const int n0 = w * 96;

    __shared__ __align__(16) float stage[16 * 772];      // 49.4KB
    __shared__ float redS[8][64], redS2[8][64];

    const unsigned short* aptr = abufG + (size_t)nb * 64 * KW2;

    float gcol[6], bcol[6];
    f32x4 acc[6][4];
    #pragma unroll
    for (int nt = 0; nt < 6; ++nt) {
        int col = n0 + nt * 16 + lr;
        gcol[nt] = on_g[col]; bcol[nt] = on_b[col];
        float bias = bo[col] + bp[col];
        #pragma unroll
        for (int Mt = 0; Mt < 4; ++Mt) acc[nt][Mt] = (f32x4){bias, bias, bias, bias};
    }

    // ---- K-loop: 12 steps, fully unrolled, no barriers -------------------
    #pragma unroll
    for (int ks = 0; ks < 12; ++ks) {
        bf16x8 aw[4];
        #pragma unroll
        for (int Mt = 0; Mt < 4; ++Mt)
            aw[Mt] = *(const bf16x8*)(aptr + (Mt * 16 + lr) * KW2 + ks * 32 + kg * 8);
        __builtin_amdgcn_s_setprio(1);
        #pragma unroll
        for (int nt = 0; nt < 6; ++nt) {
            bf16x8 b = *(const bf16x8*)(Wcat + (size_t)(n0 + nt * 16 + lr) * KW2 + ks * 32 + kg * 8);
            #pragma unroll
            for (int Mt = 0; Mt < 4; ++Mt)
                acc[nt][Mt] = __builtin_amdgcn_mfma_f32_16x16x32_bf16(aw[Mt], b, acc[nt][Mt], 0, 0, 0);
        }
        __builtin_amdgcn_s_setprio(0);
    }

    // ---- LN stats --------------------------------------------------------
    #pragma unroll
    for (int Mt = 0; Mt < 4; ++Mt)
        #pragma unroll
        for (int r = 0; r < 4; ++r) {
            float s = 0.f, q = 0.f;
            #pragma unroll
            for (int nt = 0; nt < 6; ++nt) { float v = acc[nt][Mt][r]; s += v; q += v * v; }
            #pragma unroll
            for (int off = 8; off; off >>= 1) {
                s += __shfl_xor(s, off, 64);
                q += __shfl_xor(q, off, 64);
            }
            if (lr == 0) {
                int tok = Mt * 16 + kg * 4 + r;
                redS [w][tok] = s;
                redS2[w][tok] = q;
            }
        }
    __syncthreads();
    float mA[4][4], riA[4][4];
    #pragma unroll
    for (int Mt = 0; Mt < 4; ++Mt)
        #pragma unroll
        for (int r = 0; r < 4; ++r) {
            int tok = Mt * 16 + kg * 4 + r;
            float ts = 0.f, tq = 0.f;
            #pragma unroll
            for (int ww = 0; ww < 8; ++ww) { ts += redS[ww][tok]; tq += redS2[ww][tok]; }
            float mm  = ts / DM;
            float var = tq / DM - mm * mm;
            mA[Mt][r]  = mm;
            riA[Mt][r] = 1.0f / sqrtf(var + EPSF);
        }

    // ---- staged coalesced write: one 16-row tile (= one source row) at a time
    #pragma unroll
    for (int Mt = 0; Mt < 4; ++Mt) {
        __syncthreads();
        #pragma unroll
        for (int nt = 0; nt < 6; ++nt)
            #pragma unroll
            for (int r = 0; r < 4; ++r)
                stage[(kg * 4 + r) * 772 + n0 + nt * 16 + lr] =
                    (acc[nt][Mt][r] - mA[Mt][r]) * riA[Mt][r] * gcol[nt] + bcol[nt];
        __syncthreads();
        int gr = nb * 4 + Mt;
        if (gr < Nrows) {
            #pragma unroll
            for (int v = 0; v < 6; ++v) {
                int f = v * 512 + tid;          // 0..3071
                int row = f / 192, c4 = f - row * 192;
                if (row < NTOK)
                    *(float4*)(out + ((size_t)gr * NTOK + row) * DM + c4 * 4) =
                        *(const float4*)(&stage[row * 772 + c4 * 4]);
            }
        }
    }
}

// ---------------------------------------------------------------------------
// Fallback: fused kernel (used only if ws_size too small for abuf).
// ---------------------------------------------------------------------------
__global__ __launch_bounds__(512, 4) void row_fused_kernel(
    const float* __restrict__ state,
    const float* __restrict__ w_scalar, const float* __restrict__ b_scalar,
    const float* __restrict__ w_patch,  const float* __restrict__ b_patch,
    const float* __restrict__ feat_emb,
    const float* __restrict__ pn_g, const float* __restrict__ pn_b,
    const unsigned short* __restrict__ KWb, const float* __restrict__ kqb,
    const unsigned short* __restrict__ Wcat,
    const float* __restrict__ bp, const float* __restrict__ bo,
    const float* __restrict__ on_g, const float* __restrict__ on_b,
    float* __restrict__ out, int Nrows)
{
    int tid = threadIdx.x;
    int w = tid >> 6, lane = tid & 63;
    int kg = lane >> 4, lr = lane & 15;
    int nb = blockIdx.x;

    __shared__ __align__(16) char bufA[64 * 512];
    __shared__ __align__(16) char pebf[64 * 256];
    __shared__ float srow[4 * 36];
    __shared__ float redS[8][64], redS2[8][64];

    float* peF = (float*)bufA;

    if (tid < 4 * 36) {
        int rr = tid / 36;
        int gr = nb * 4 + rr;
        srow[tid] = (gr < Nrows) ? state[(size_t)gr * 36 + (tid - rr * 36)] : 0.f;
    }
    __syncthreads();

    for (int idx = tid; idx < 4 * NTOK * DP; idx += 512) {
        int rr  = idx / (NTOK * DP);
        int rem = idx - rr * (NTOK * DP);
        int t = rem >> 7, d = rem & 127;
        const float* sr = &srow[rr * 36];
        float val;
        if (t == 0) {
            val = sr[5]  * w_scalar[0 * DP + d] + b_scalar[0 * DP + d] + feat_emb[0 * DP + d];
        } else if (t == 1) {
            val = sr[11] * w_scalar[1 * DP + d] + b_scalar[1 * DP + d] + feat_emb[1 * DP + d];
        } else if (t == 14) {
            val = sr[35] * w_scalar[2 * DP + d] + b_scalar[2 * DP + d] + feat_emb[5 * DP + d];
        } else {
            int f = (t - 2) / 4;
            int k = (t - 2) % 4;
            const float* pr = &sr[(2 + f) * 6];
            float acc = b_patch[f * DP + d] + feat_emb[(2 + f) * DP + d];
            for (int p = 0; p < 3; ++p) acc += pr[k + p] * w_patch[(f * 3 + p) * DP + d];
            val = acc;
        }
        peF[(rr * 16 + t) * DP + d] = val;
    }
    __syncthreads();

    const int h = w >> 1;
    bf16x8 ka[4][4];
    float4 kqv[4];
    {
        const unsigned short* kwh = KWb + (size_t)h * NP * DP;
        #pragma unroll
        for (int Mt = 0; Mt < 4; ++Mt) {
            #pragma unroll
            for (int kk = 0; kk < 4; ++kk)
                ka[Mt][kk] = *(const bf16x8*)(kwh + (Mt * 16 + lr) * DP + kk * 32 + kg * 8);
            kqv[Mt] = *(const float4*)(kqb + h * 64 + Mt * 16 + kg * 4);
        }
    }

    {
        int g = tid >> 3, ln = tid & 7;
        int t = g & 15;
        int gr = nb * 4 + (g >> 4);
        if (t == 15 || gr >= Nrows) {
            for (int d = ln; d < DP; d += 8)
                *(unsigned short*)(pebf + swzP(g, d * 2)) = 0;
        } else {
            float s = 0.f, s2 = 0.f;
            for (int d = ln; d < DP; d += 8) { float x = peF[g * DP + d]; s += x; s2 += x * x; }
            for (int off = 4; off; off >>= 1) {
                s  += __shfl_xor(s,  off, 64);
                s2 += __shfl_xor(s2, off, 64);
            }
            float m   = s / DP;
            float var = s2 / DP - m * m;
            float rin = 1.0f / sqrtf(var + EPSF);
            for (int d = ln; d < DP; d += 8) {
                float x = (peF[g * DP + d] - m) * rin * pn_g[d] + pn_b[d];
                *(unsigned short*)(pebf + swzP(g, d * 2)) = f2bf(x);
            }
        }
    }
    __syncthreads();

    {
        int Nt0 = (w & 1) * 2;
        #pragma unroll
        for (int Ntl = 0; Ntl < 2; ++Ntl) {
            int Nt = Nt0 + Ntl;
            bf16x8 qb[4];
            #pragma unroll
            for (int kk = 0; kk < 4; ++kk)
                qb[kk] = *(const bf16x8*)(pebf + swzP(Nt * 16 + lr, (kk * 32 + kg * 8) * 2));
            f32x4 sacc[4];
            #pragma unroll
            for (int Mt = 0; Mt < 4; ++Mt) sacc[Mt] = (f32x4){0.f, 0.f, 0.f, 0.f};
            #pragma unroll
            for (int kk = 0; kk < 4; ++kk)
                #pragma unroll
                for (int Mt = 0; Mt < 4; ++Mt)
                    sacc[Mt] = __builtin_amdgcn_mfma_f32_16x16x32_bf16(ka[Mt][kk], qb[kk], sacc[Mt], 0, 0, 0);
            #pragma unroll
            for (int Mt = 0; Mt < 4; ++Mt) {
                sacc[Mt][0] += kqv[Mt].x; sacc[Mt][1] += kqv[Mt].y;
                sacc[Mt][2] += kqv[Mt].z; sacc[Mt][3] += kqv[Mt].w;
            }
            float mx = -3.4e38f;
            #pragma unroll
            for (int Mt = 0; Mt < 4; ++Mt)
                #pragma unroll
                for (int r = 0; r < 4; ++r) mx = fmaxf(mx, sacc[Mt][r]);
            mx = fmaxf(mx, __shfl_xor(mx, 16, 64));
            mx = fmaxf(mx, __shfl_xor(mx, 32, 64));
            float sum = 0.f;
            f32x4 ee[4];
            #pragma unroll
            for (int Mt = 0; Mt < 4; ++Mt)
                #pragma unroll
                for (int r = 0; r < 4; ++r) { float e = __expf(sacc[Mt][r] - mx); ee[Mt][r] = e; sum += e; }
            sum += __shfl_xor(sum, 16, 64);
            sum += __shfl_xor(sum, 32, 64);
            float inv = 1.0f / sum;
            #pragma unroll
            for (int Mt = 0; Mt < 4; ++Mt)
                #pragma unroll
                for (int r = 0; r < 4; ++r) {
                    int c = h * 64 + Mt * 16 + kg * 4 + r;
                    *(unsigned short*)(bufA + swzB(Nt * 16 + lr, c * 2)) = f2bf(ee[Mt][r] * inv);
                }
        }
    }
    __syncthreads();

    const int n0 = w * 96;
    #pragma unroll
    for (int half = 0; half < 2; ++half) {
        f32x4 acc[6][2];
        #pragma unroll
        for (int nt = 0; nt < 6; ++nt) {
            int col = n0 + nt * 16 + lr;
            float bias = bo[col] + bp[col];
            acc[nt][0] = (f32x4){bias, bias, bias, bias};
            acc[nt][1] = (f32x4){bias, bias, bias, bias};
        }
        #pragma unroll
        for (int kkc = 0; kkc < 3; ++kkc) {
            #pragma unroll
            for (int kk = 0; kk < 4; ++kk) {
                bf16x8 aw0, aw1;
                if (kkc < 2) {
                    aw0 = *(const bf16x8*)(bufA + swzB((half * 2 + 0) * 16 + lr, (kkc * 128 + kk * 32 + kg * 8) * 2));
                    aw1 = *(const bf16x8*)(bufA + swzB((half * 2 + 1) * 16 + lr, (kkc * 128 + kk * 32 + kg * 8) * 2));
                } else {
                    aw0 = *(const bf16x8*)(pebf + swzP((half * 2 + 0) * 16 + lr, (kk * 32 + kg * 8) * 2));
                    aw1 = *(const bf16x8*)(pebf + swzP((half * 2 + 1) * 16 + lr, (kk * 32 + kg * 8) * 2));
                }
                int ks = kkc * 4 + kk;
                #pragma unroll
                for (int nt = 0; nt < 6; ++nt) {
                    bf16x8 b = *(const bf16x8*)(Wcat + (size_t)(n0 + nt * 16 + lr) * KW2 + ks * 32 + kg * 8);
                    acc[nt][0] = __builtin_amdgcn_mfma_f32_16x16x32_bf16(aw0, b, acc[nt][0], 0, 0, 0);
                    acc[nt][1] = __builtin_amdgcn_mfma_f32_16x16x32_bf16(aw1, b, acc[nt][1], 0, 0, 0);
                }
            }
        }
        #pragma unroll
        for (int Mtl = 0; Mtl < 2; ++Mtl)
            #pragma unroll
            for (int r = 0; r < 4; ++r) {
                float s = 0.f, q = 0.f;
                #pragma unroll
                for (int nt = 0; nt < 6; ++nt) { float v = acc[nt][Mtl][r]; s += v; q += v * v; }
                #pragma unroll
                for (int off = 8; off; off >>= 1) {
                    s += __shfl_xor(s, off, 64);
                    q += __shfl_xor(q, off, 64);
                }
                if (lr == 0) {
                    int tok = (half * 2 + Mtl) * 16 + kg * 4 + r;
                    redS [w][tok] = s;
                    redS2[w][tok] = q;
                }
            }
        __syncthreads();
        #pragma unroll
        for (int Mtl = 0; Mtl < 2; ++Mtl) {
            float mA[4], riA[4];
            #pragma unroll
            for (int r = 0; r < 4; ++r) {
                int tok = (half * 2 + Mtl) * 16 + kg * 4 + r;
                float ts = 0.f, tq = 0.f;
                #pragma unroll
                for (int ww = 0; ww < 8; ++ww) { ts += redS[ww][tok]; tq += redS2[ww][tok]; }
                float mm  = ts / DM;
                float var = tq / DM - mm * mm;
                mA[r]  = mm;
                riA[r] = 1.0f / sqrtf(var + EPSF);
            }
            #pragma unroll
            for (int nt = 0; nt < 6; ++nt) {
                int col = n0 + nt * 16 + lr;
                float g = on_g[col], bb = on_b[col];
                #pragma unroll
                for (int r = 0; r < 4; ++r) {
                    int tok = (half * 2 + Mtl) * 16 + kg * 4 + r;
                    int t = tok & 15, rr = tok >> 4;
                    int gr = nb * 4 + rr;
                    if (t < NTOK && gr < Nrows)
                        out[((size_t)gr * NTOK + t) * DM + col] =
                            (acc[nt][Mtl][r] - mA[r]) * riA[r] * g + bb;
                }
            }
        }
    }
}

extern "C" void kernel_launch(void* const* d_in, const int* in_sizes, int n_in,
                              void* d_out, int out_size, void* d_ws, size_t ws_size,
                              hipStream_t stream) {
    const float* state    = (const float*)d_in[0];
    const float* w_scalar = (const float*)d_in[1];
    const float* b_scalar = (const float*)d_in[2];
    const float* w_patch  = (const float*)d_in[3];
    const float* b_patch  = (const float*)d_in[4];
    const float* feat_emb = (const float*)d_in[5];
    const float* pn_g     = (const float*)d_in[6];
    const float* pn_b     = (const float*)d_in[7];
    const float* wq       = (const float*)d_in[8];
    const float* bq       = (const float*)d_in[9];
    const float* wk       = (const float*)d_in[10];
    const float* bk       = (const float*)d_in[11];
    const float* wv       = (const float*)d_in[12];
    const float* bv       = (const float*)d_in[13];
    const float* wp       = (const float*)d_in[14];
    const float* bp       = (const float*)d_in[15];
    const float* wo       = (const float*)d_in[16];
    const float* bo       = (const float*)d_in[17];
    const float* on_g     = (const float*)d_in[18];
    const float* on_b     = (const float*)d_in[19];
    const float* protos   = (const float*)d_in[20];
    float* out = (float*)d_out;

    float*          Kraw = (float*)d_ws;                    // 49152 f32
    float*          Vf   = Kraw + 256 * HD;                 // 49152 f32
    float*          kqbp = Vf + NP * DM;                    // 256   f32
    unsigned short* KWb  = (unsigned short*)(kqbp + 256);   // 32768 us
    unsigned short* Wcat = KWb + 256 * DP;                  // 294912 us
    unsigned short* abufG = Wcat + (size_t)DM * KW2;

    int N = in_sizes[0] / 36;
    int nblkA = (N + 1) / 2;
    int nblkB = (N + 3) / 4;
    size_t tokrows = (size_t)nblkB * 64;
    size_t need = 1049600ull + tokrows * KW2 * 2ull;        // base + abuf bytes

    hipLaunchKernelGGL(kv_kernel, dim3(256), dim3(192), 0, stream,
                       protos, wk, bk, wv, bv, Kraw, Vf);
    hipLaunchKernelGGL(fold_kernel, dim3(640), dim3(256), 0, stream,
                       Kraw, Vf, wq, bq, wo, wp, KWb, kqbp, Wcat);

    if (ws_size >= need) {
        hipLaunchKernelGGL(phaseA_kernel, dim3(nblkA), dim3(256), 0, stream,
                           state, w_scalar, b_scalar, w_patch, b_patch, feat_emb,
                           pn_g, pn_b, KWb, kqbp, abufG, N);
        hipLaunchKernelGGL(phaseB_kernel, dim3(nblkB), dim3(512), 0, stream,
                           abufG, Wcat, bp, bo, on_g, on_b, out, N);
    } else {
        hipLaunchKernelGGL(row_fused_kernel, dim3(nblkB), dim3(512), 0, stream,
                           state, w_scalar, b_scalar, w_patch, b_patch, feat_emb,
                           pn_g, pn_b, KWb, kqbp, Wcat, bp, bo, on_g, on_b,
                           out, N);
    }
}

// Round 18
// 265.086 us; speedup vs baseline: 1.8826x; 1.1249x over previous
//
#include <hip/hip_runtime.h>

#define NTOK 15
#define DP   128
#define DM   768
#define NH   4
#define HD   192
#define NP   64
#define EPSF 1e-5f
#define KW2  384    // [attn(256) | pe(128)]
#define ABSTR 528   // phaseA attn LDS row stride in bytes (132 f32: +4 banks/row)

typedef __attribute__((ext_vector_type(8))) short bf16x8;   // 8 bf16 = 4 VGPR
typedef __attribute__((ext_vector_type(4))) float f32x4;
typedef __attribute__((ext_vector_type(4))) unsigned short us4;

__device__ __forceinline__ unsigned short f2bf(float x) {
    unsigned u = __float_as_uint(x);
    u = (u + 0x7FFF + ((u >> 16) & 1)) >> 16;   // RNE
    return (unsigned short)u;
}
// swizzled LDS byte addresses (row strides 256B / 512B)
__device__ __forceinline__ int swzP(int row, int b) { return row * 256 + (b ^ ((row & 7) << 4)); }
__device__ __forceinline__ int swzB(int row, int b) { return row * 512 + (b ^ ((row & 7) << 4)); }

// ---------------------------------------------------------------------------
// P1 (merged kv+fold): blocks 0..255 (hp = h*64+p) recompute their own
// K/V 192-slices from protos (75 MFLOP total, same as old kv's K part),
// then fold into KWb/kqb/Wcat. Blocks 256..639: wp transpose into Wcat.
// Eliminates the kv launch + Kraw/Vf round-trip.
// ---------------------------------------------------------------------------
__global__ __launch_bounds__(256) void fold_kernel(
    const float* __restrict__ protos,
    const float* __restrict__ wk, const float* __restrict__ bk,
    const float* __restrict__ wv, const float* __restrict__ bv,
    const float* __restrict__ wq, const float* __restrict__ bq,
    const float* __restrict__ wo, const float* __restrict__ wp,
    unsigned short* __restrict__ KWb, float* __restrict__ kqb,
    unsigned short* __restrict__ Wcat)
{
    int b = blockIdx.x, tid = threadIdx.x;
    if (b >= 256) {
        int idx = (b - 256) * 256 + tid;
        int j = idx >> 7, d = idx & 127;
        Wcat[(size_t)j * KW2 + 256 + d] = f2bf(wp[d * DM + j]);
        return;
    }
    int hp = b, h = hp >> 6, p = hp & 63;
    __shared__ float prow[DM];
    __shared__ float Kl[HD], Vl[HD];
    for (int i = tid; i < DM; i += 256) prow[i] = protos[p * DM + i];
    __syncthreads();
    // recompute K/V slice for (p, h): 192 threads, coalesced wk/wv reads
    if (tid < HD) {
        float aK = bk[h * HD + tid], aV = bv[h * HD + tid];
        for (int e = 0; e < DM; ++e) {
            float pr = prow[e];
            aK += pr * wk[e * DM + h * HD + tid];
            aV += pr * wv[e * DM + h * HD + tid];
        }
        Kl[tid] = aK;
        Vl[tid] = aV;
    }
    __syncthreads();
    const float scale = 0.07216878364870323f;   // 1/sqrt(192)
    if (tid < DP) {
        float a = 0.f;
        for (int l = 0; l < HD; ++l) a += wq[tid * DM + h * HD + l] * Kl[l];
        KWb[hp * DP + tid] = f2bf(scale * a);
    } else if (tid == DP) {
        float a = 0.f;
        for (int l = 0; l < HD; ++l) a += bq[h * HD + l] * Kl[l];
        kqb[hp] = scale * a;
    }
    for (int jj = 0; jj < 3; ++jj) {
        int j = jj * 256 + tid;
        float a = 0.f;
        for (int l = 0; l < HD; ++l) a += wo[(h * HD + l) * DM + j] * Vl[l];
        Wcat[(size_t)j * KW2 + hp] = f2bf(a);
    }
}

// ---------------------------------------------------------------------------
// Phase A: 2 state-rows (32 token-rows) per block, 256 thr.
// Change vs r17: attn lands in LDS (aliasing dead peF, stride 528B), then one
// unified coalesced 16B-chunk copy-out of [attn|pe] rows to abufG.
// LDS ~25.5KB -> 4 blocks/CU.
// ---------------------------------------------------------------------------
__global__ __launch_bounds__(256, 4) void phaseA_kernel(
    const float* __restrict__ state,
    const float* __restrict__ w_scalar, const float* __restrict__ b_scalar,
    const float* __restrict__ w_patch,  const float* __restrict__ b_patch,
    const float* __restrict__ feat_emb,
    const float* __restrict__ pn_g, const float* __restrict__ pn_b,
    const unsigned short* __restrict__ KWb, const float* __restrict__ kqb,
    unsigned short* __restrict__ abufG, int Nrows)
{
    int tid = threadIdx.x;
    int w = tid >> 6, lane = tid & 63;
    int kg = lane >> 4, lr = lane & 15;
    int nb = blockIdx.x;
    size_t rowbase = (size_t)nb * 32;

    __shared__ __align__(16) char buf0[32 * ABSTR];   // peF f32 [32][128] -> attn bf16 [32][264]
    __shared__ __align__(16) char pebf[32 * 256];     // 8KB swizzled bf16
    __shared__ float srow[72];

    float* peF = (float*)buf0;   // stride-128 f32 view during build/LN

    if (tid < 72) {
        int rr = tid / 36;
        int gr = nb * 2 + rr;
        srow[tid] = (gr < Nrows) ? state[(size_t)gr * 36 + (tid - rr * 36)] : 0.f;
    }
    __syncthreads();

    // ---- build pe f32 (32 rows x 128) ------------------------------------
    #pragma unroll
    for (int it = 0; it < 16; ++it) {
        int idx = it * 256 + tid;
        int row = idx >> 7, d = idx & 127;
        int t = row & 15;
        const float* sr = &srow[(row >> 4) * 36];
        float val;
        if (t == 15) {
            val = 0.f;
        } else if (t == 0) {
            val = sr[5]  * w_scalar[0 * DP + d] + b_scalar[0 * DP + d] + feat_emb[0 * DP + d];
        } else if (t == 1) {
            val = sr[11] * w_scalar[1 * DP + d] + b_scalar[1 * DP + d] + feat_emb[1 * DP + d];
        } else if (t == 14) {
            val = sr[35] * w_scalar[2 * DP + d] + b_scalar[2 * DP + d] + feat_emb[5 * DP + d];
        } else {
            int f = (t - 2) / 4;
            int k = (t - 2) % 4;
            const float* pr = &sr[(2 + f) * 6];
            float acc = b_patch[f * DP + d] + feat_emb[(2 + f) * DP + d];
            for (int p = 0; p < 3; ++p) acc += pr[k + p] * w_patch[(f * 3 + p) * DP + d];
            val = acc;
        }
        peF[row * DP + d] = val;
    }
    __syncthreads();

    // ---- LayerNorm -> pebf bf16 swizzled (8 lanes per token-row) ---------
    {
        int g = tid >> 3, ln = tid & 7;     // g = 0..31
        int t = g & 15;
        int gr = nb * 2 + (g >> 4);
        if (t == 15 || gr >= Nrows) {
            for (int d = ln; d < DP; d += 8)
                *(unsigned short*)(pebf + swzP(g, d * 2)) = 0;
        } else {
            float s = 0.f, s2 = 0.f;
            for (int d = ln; d < DP; d += 8) { float x = peF[g * DP + d]; s += x; s2 += x * x; }
            for (int off = 4; off; off >>= 1) {
                s  += __shfl_xor(s,  off, 64);
                s2 += __shfl_xor(s2, off, 64);
            }
            float m   = s / DP;
            float var = s2 / DP - m * m;
            float rin = 1.0f / sqrtf(var + EPSF);
            for (int d = ln; d < DP; d += 8) {
                float x = (peF[g * DP + d] - m) * rin * pn_g[d] + pn_b[d];
                *(unsigned short*)(pebf + swzP(g, d * 2)) = f2bf(x);
            }
        }
    }
    __syncthreads();   // peF f32 dead; buf0 becomes attn bf16 (stride ABSTR)

    // ---- scores = KW @ pe^T + kqb; softmax; attn -> buf0 (LDS) -----------
    {
        const int h = w;                       // wave == head
        const unsigned short* kwh = KWb + (size_t)h * NP * DP;
        bf16x8 ka[4][4];
        float4 kqv[4];
        #pragma unroll
        for (int Mt = 0; Mt < 4; ++Mt) {
            #pragma unroll
            for (int kk = 0; kk < 4; ++kk)
                ka[Mt][kk] = *(const bf16x8*)(kwh + (Mt * 16 + lr) * DP + kk * 32 + kg * 8);
            kqv[Mt] = *(const float4*)(kqb + h * 64 + Mt * 16 + kg * 4);
        }
        #pragma unroll
        for (int Ntl = 0; Ntl < 2; ++Ntl) {
            bf16x8 qb[4];
            #pragma unroll
            for (int kk = 0; kk < 4; ++kk)
                qb[kk] = *(const bf16x8*)(pebf + swzP(Ntl * 16 + lr, (kk * 32 + kg * 8) * 2));
            f32x4 sacc[4];
            #pragma unroll
            for (int Mt = 0; Mt < 4; ++Mt) sacc[Mt] = (f32x4){0.f, 0.f, 0.f, 0.f};
            #pragma unroll
            for (int kk = 0; kk < 4; ++kk)
                #pragma unroll
                for (int Mt = 0; Mt < 4; ++Mt)
                    sacc[Mt] = __builtin_amdgcn_mfma_f32_16x16x32_bf16(ka[Mt][kk], qb[kk], sacc[Mt], 0, 0, 0);
            #pragma unroll
            for (int Mt = 0; Mt < 4; ++Mt) {
                sacc[Mt][0] += kqv[Mt].x; sacc[Mt][1] += kqv[Mt].y;
                sacc[Mt][2] += kqv[Mt].z; sacc[Mt][3] += kqv[Mt].w;
            }
            float mx = -3.4e38f;
            #pragma unroll
            for (int Mt = 0; Mt < 4; ++Mt)
                #pragma unroll
                for (int r = 0; r < 4; ++r) mx = fmaxf(mx, sacc[Mt][r]);
            mx = fmaxf(mx, __shfl_xor(mx, 16, 64));
            mx = fmaxf(mx, __shfl_xor(mx, 32, 64));
            float sum = 0.f;
            f32x4 ee[4];
            #pragma unroll
            for (int Mt = 0; Mt < 4; ++Mt)
                #pragma unroll
                for (int r = 0; r < 4; ++r) { float e = __expf(sacc[Mt][r] - mx); ee[Mt][r] = e; sum += e; }
            sum += __shfl_xor(sum, 16, 64);
            sum += __shfl_xor(sum, 32, 64);
            float inv = 1.0f / sum;
            int row = Ntl * 16 + lr;
            #pragma unroll
            for (int Mt = 0; Mt < 4; ++Mt) {
                us4 v = { f2bf(ee[Mt][0] * inv), f2bf(ee[Mt][1] * inv),
                          f2bf(ee[Mt][2] * inv), f2bf(ee[Mt][3] * inv) };
                *(us4*)(buf0 + row * ABSTR + (h * 64 + Mt * 16 + kg * 4) * 2) = v;
            }
        }
    }
    __syncthreads();   // all waves' attn landed in LDS

    // ---- unified coalesced copy-out: [attn(512B) | pe(256B)] per row -----
    #pragma unroll
    for (int c = 0; c < 6; ++c) {
        int idx = c * 256 + tid;            // 0..1535
        int row = idx / 48, chunk = idx % 48;
        bf16x8 v;
        if (chunk < 32) v = *(const bf16x8*)(buf0 + row * ABSTR + chunk * 16);
        else            v = *(const bf16x8*)(pebf + swzP(row, (chunk - 32) * 16));
        *(bf16x8*)(abufG + (rowbase + row) * KW2 + chunk * 8) = v;
    }
}

// ---------------------------------------------------------------------------
// Phase B (frozen r11 config): out = LN(A[64x384] @ Wcat^T + bias).
// Direct global A reads, no barriers in K-loop; 16-row staged coalesced write;
// 2 blocks/CU (verified optimum — 4 blocks/CU thrashes L2 write-combining).
// ---------------------------------------------------------------------------
__global__ __launch_bounds__(512, 2) void phaseB_kernel(
    const unsigned short* __restrict__ abufG,
    const unsigned short* __restrict__ Wcat,
    const float* __restrict__ bp, const float* __restrict__ bo,
    const float* __restrict__ on_g, const float* __restrict__ on_b,
    float* __restrict__ out, int Nrows)
{
    int tid = threadIdx.x;
    int w = tid >> 6, lane = tid & 63;
    int kg = lane >> 4, lr = lane & 15;
    int nb = blockIdx.x;
    const int n0 = w * 96;

    __shared__ __align__(16) float stage[16 * 772];      // 49.4KB
    __shared__ float redS[8][64], redS2[8][64];

    const unsigned short* aptr = abufG + (size_t)nb * 64 * KW2;

    float gcol[6], bcol[6];
    f32x4 acc[6][4];
    #pragma unroll
    for (int nt = 0; nt < 6; ++nt) {
        int col = n0 + nt * 16 + lr;
        gcol[nt] = on_g[col]; bcol[nt] = on_b[col];
        float bias = bo[col] + bp[col];
        #pragma unroll
        for (int Mt = 0; Mt < 4; ++Mt) acc[nt][Mt] = (f32x4){bias, bias, bias, bias};
    }

    // ---- K-loop: 12 steps, fully unrolled, no barriers -------------------
    #pragma unroll
    for (int ks = 0; ks < 12; ++ks) {
        bf16x8 aw[4];
        #pragma unroll
        for (int Mt = 0; Mt < 4; ++Mt)
            aw[Mt] = *(const bf16x8*)(aptr + (Mt * 16 + lr) * KW2 + ks * 32 + kg * 8);
        __builtin_amdgcn_s_setprio(1);
        #pragma unroll
        for (int nt = 0; nt < 6; ++nt) {
            bf16x8 b = *(const bf16x8*)(Wcat + (size_t)(n0 + nt * 16 + lr) * KW2 + ks * 32 + kg * 8);
            #pragma unroll
            for (int Mt = 0; Mt < 4; ++Mt)
                acc[nt][Mt] = __builtin_amdgcn_mfma_f32_16x16x32_bf16(aw[Mt], b, acc[nt][Mt], 0, 0, 0);
        }
        __builtin_amdgcn_s_setprio(0);
    }

    // ---- LN stats --------------------------------------------------------
    #pragma unroll
    for (int Mt = 0; Mt < 4; ++Mt)
        #pragma unroll
        for (int r = 0; r < 4; ++r) {
            float s = 0.f, q = 0.f;
            #pragma unroll
            for (int nt = 0; nt < 6; ++nt) { float v = acc[nt][Mt][r]; s += v; q += v * v; }
            #pragma unroll
            for (int off = 8; off; off >>= 1) {
                s += __shfl_xor(s, off, 64);
                q += __shfl_xor(q, off, 64);
            }
            if (lr == 0) {
                int tok = Mt * 16 + kg * 4 + r;
                redS [w][tok] = s;
                redS2[w][tok] = q;
            }
        }
    __syncthreads();
    float mA[4][4], riA[4][4];
    #pragma unroll
    for (int Mt = 0; Mt < 4; ++Mt)
        #pragma unroll
        for (int r = 0; r < 4; ++r) {
            int tok = Mt * 16 + kg * 4 + r;
            float ts = 0.f, tq = 0.f;
            #pragma unroll
            for (int ww = 0; ww < 8; ++ww) { ts += redS[ww][tok]; tq += redS2[ww][tok]; }
            float mm  = ts / DM;
            float var = tq / DM - mm * mm;
            mA[Mt][r]  = mm;
            riA[Mt][r] = 1.0f / sqrtf(var + EPSF);
        }

    // ---- staged coalesced write: one 16-row tile (= one source row) at a time
    #pragma unroll
    for (int Mt = 0; Mt < 4; ++Mt) {
        __syncthreads();
        #pragma unroll
        for (int nt = 0; nt < 6; ++nt)
            #pragma unroll
            for (int r = 0; r < 4; ++r)
                stage[(kg * 4 + r) * 772 + n0 + nt * 16 + lr] =
                    (acc[nt][Mt][r] - mA[Mt][r]) * riA[Mt][r] * gcol[nt] + bcol[nt];
        __syncthreads();
        int gr = nb * 4 + Mt;
        if (gr < Nrows) {
            #pragma unroll
            for (int v = 0; v < 6; ++v) {
                int f = v * 512 + tid;          // 0..3071
                int row = f / 192, c4 = f - row * 192;
                if (row < NTOK)
                    *(float4*)(out + ((size_t)gr * NTOK + row) * DM + c4 * 4) =
                        *(const float4*)(&stage[row * 772 + c4 * 4]);
            }
        }
    }
}

extern "C" void kernel_launch(void* const* d_in, const int* in_sizes, int n_in,
                              void* d_out, int out_size, void* d_ws, size_t ws_size,
                              hipStream_t stream) {
    const float* state    = (const float*)d_in[0];
    const float* w_scalar = (const float*)d_in[1];
    const float* b_scalar = (const float*)d_in[2];
    const float* w_patch  = (const float*)d_in[3];
    const float* b_patch  = (const float*)d_in[4];
    const float* feat_emb = (const float*)d_in[5];
    const float* pn_g     = (const float*)d_in[6];
    const float* pn_b     = (const float*)d_in[7];
    const float* wq       = (const float*)d_in[8];
    const float* bq       = (const float*)d_in[9];
    const float* wk       = (const float*)d_in[10];
    const float* bk       = (const float*)d_in[11];
    const float* wv       = (const float*)d_in[12];
    const float* bv       = (const float*)d_in[13];
    const float* wp       = (const float*)d_in[14];
    const float* bp       = (const float*)d_in[15];
    const float* wo       = (const float*)d_in[16];
    const float* bo       = (const float*)d_in[17];
    const float* on_g     = (const float*)d_in[18];
    const float* on_b     = (const float*)d_in[19];
    const float* protos   = (const float*)d_in[20];
    float* out = (float*)d_out;

    float*          kqbp  = (float*)d_ws;                   // 256 f32
    unsigned short* KWb   = (unsigned short*)(kqbp + 256);  // 256*128 bf16
    unsigned short* Wcat  = KWb + 256 * DP;                 // 768*384 bf16
    unsigned short* abufG = Wcat + (size_t)DM * KW2;

    int N = in_sizes[0] / 36;
    int nblkA = (N + 1) / 2;
    int nblkB = (N + 3) / 4;
    size_t tokrows = (size_t)nblkB * 64;
    size_t need = 1024ull + 65536ull + 589824ull + tokrows * KW2 * 2ull;

    hipLaunchKernelGGL(fold_kernel, dim3(640), dim3(256), 0, stream,
                       protos, wk, bk, wv, bv, wq, bq, wo, wp,
                       KWb, kqbp, Wcat);
    if (ws_size >= need) {
        hipLaunchKernelGGL(phaseA_kernel, dim3(nblkA), dim3(256), 0, stream,
                           state, w_scalar, b_scalar, w_patch, b_patch, feat_emb,
                           pn_g, pn_b, KWb, kqbp, abufG, N);
        hipLaunchKernelGGL(phaseB_kernel, dim3(nblkB), dim3(512), 0, stream,
                           abufG, Wcat, bp, bo, on_g, on_b, out, N);
    }
}